// Round 8
// baseline (6352.431 us; speedup 1.0000x reference)
//
#include <hip/hip_runtime.h>
#include <hip/hip_fp16.h>
#include <stdint.h>

#define B_ 64
#define T_ 2048
#define I_ 16
#define H_ 256
#define G_ 768   // 3*H

typedef _Float16 f16;
typedef _Float16 half2_t __attribute__((ext_vector_type(2)));
typedef uint32_t u32x4 __attribute__((ext_vector_type(4)));

// ---------- fast math helpers ----------
__device__ __forceinline__ float fast_rcp(float x) {
#if __has_builtin(__builtin_amdgcn_rcpf)
    return __builtin_amdgcn_rcpf(x);
#else
    return 1.0f / x;
#endif
}
__device__ __forceinline__ float sigmoid_f(float x) {
    return fast_rcp(1.0f + __expf(-x));
}
__device__ __forceinline__ float tanh_f(float x) {
    float e = __expf(2.0f * x);
    return 1.0f - 2.0f * fast_rcp(e + 1.0f);
}

__device__ __forceinline__ float fdot2(uint32_t a, uint32_t b, float c) {
#if __has_builtin(__builtin_amdgcn_fdot2)
    return __builtin_amdgcn_fdot2(__builtin_bit_cast(half2_t, a),
                                  __builtin_bit_cast(half2_t, b), c, false);
#else
    half2_t ha = __builtin_bit_cast(half2_t, a), hb = __builtin_bit_cast(half2_t, b);
    return c + (float)ha.x * (float)hb.x + (float)ha.y * (float)hb.y;
#endif
}
__device__ __forceinline__ float dot_u4(u32x4 w, u32x4 h, float acc) {
    acc = fdot2(w.x, h.x, acc);
    acc = fdot2(w.y, h.y, acc);
    acc = fdot2(w.z, h.z, acc);
    acc = fdot2(w.w, h.w, acc);
    return acc;
}

// ---------- weight fp32 -> packed fp16 conversion ----------
// dword layout (all k-major now):
//   [0,98304)       Whh0T : u32x4 u = k8*768 + row  (row<768, k8<32)
//   [98304,196608)  Whh1T : same
//   [196608,294912) Wih1T : u32x4 u = k8*768 + g
//   [294912,327680) W1T   : u32x4 u = k8*256 + g
__global__ __launch_bounds__(256) void cvt_weights(const float* __restrict__ whh0,
                                                   const float* __restrict__ whh1,
                                                   const float* __restrict__ wih1,
                                                   const float* __restrict__ w1,
                                                   uint32_t* __restrict__ out) {
    int idx = blockIdx.x * 256 + threadIdx.x;
    if (idx >= 327680) return;
    const float* s;
    if (idx < 196608) {
        const float* w = (idx < 98304) ? whh0 : whh1;
        int local = (idx < 98304) ? idx : idx - 98304;
        int u4 = local >> 2, d = local & 3;
        int k8 = u4 / 768, row = u4 - k8 * 768;
        s = w + (size_t)row * 256 + k8 * 8 + d * 2;
    } else if (idx < 294912) {
        int local = idx - 196608;
        int u4 = local >> 2, d = local & 3;
        int k8 = u4 / 768, g = u4 - k8 * 768;
        s = wih1 + (size_t)g * 256 + k8 * 8 + d * 2;
    } else {
        int local = idx - 294912;
        int u4 = local >> 2, d = local & 3;
        int k8 = u4 >> 8, g = u4 & 255;
        s = w1 + (size_t)g * 256 + k8 * 8 + d * 2;
    }
    half2_t h;
    h.x = (f16)s[0];
    h.y = (f16)s[1];
    out[idx] = __builtin_bit_cast(uint32_t, h);
}

// =======================================================================
// role bodies (all 256 threads)
// =======================================================================

// ---------- xg0 = bih0 + x @ Wih0^T (K=16, fp32), one 64-row tile ----------
__device__ __forceinline__ void xg0_body(const float* __restrict__ x,
        const float* __restrict__ wih0, const float* __restrict__ bih0,
        float* __restrict__ xg, int t0, int C, int blk, char* smem) {
    float (*xs)[16] = (float(*)[16])smem;
    int tid = threadIdx.x;
    int m0 = blk * 64;
    {
        int r = tid >> 2, c4 = (tid & 3) * 4;
        int m = m0 + r;
        int b = m / C, tl = m - b * C;
        float4 v = *(const float4*)(x + (size_t)(b * T_ + t0 + tl) * I_ + c4);
        *(float4*)&xs[r][c4] = v;
    }
    __syncthreads();
    #pragma unroll
    for (int gi = 0; gi < 3; ++gi) {
        int g = gi * 256 + tid;
        const float4* wr = (const float4*)(wih0 + (size_t)g * I_);
        float4 w0 = wr[0], w1 = wr[1], w2 = wr[2], w3 = wr[3];
        float bias = bih0[g];
        float* outp = xg + (size_t)m0 * G_ + g;
        for (int m = 0; m < 64; ++m) {
            const float4* xr4 = (const float4*)xs[m];
            float4 a0 = xr4[0], a1 = xr4[1], a2 = xr4[2], a3 = xr4[3];
            float acc = bias;
            acc += a0.x*w0.x + a0.y*w0.y + a0.z*w0.z + a0.w*w0.w;
            acc += a1.x*w1.x + a1.y*w1.y + a1.z*w1.z + a1.w*w1.w;
            acc += a2.x*w2.x + a2.y*w2.y + a2.z*w2.z + a2.w*w2.w;
            acc += a3.x*w3.x + a3.y*w3.y + a3.z*w3.z + a3.w*w3.w;
            outp[(size_t)m * G_] = acc;
        }
    }
}

// ---------- regressor, 8g x 8m register tile, one 64-row tile ----------
__device__ __forceinline__ void reg_body(const f16* __restrict__ h2,
        const uint32_t* __restrict__ w1T, const float* __restrict__ b1,
        const float* __restrict__ w2, const float* __restrict__ b2,
        float* __restrict__ out, int t0, int C, int lgC, int blk, char* smem) {
    u32x4 (*hs)[32] = (u32x4(*)[32])smem;            // 32 KB
    float (*red)[8] = (float(*)[8])(smem + 32768);   // [8][8]
    int tid = threadIdx.x;
    int m0 = blk * 64;
    const u32x4* hsrc = (const u32x4*)h2 + (size_t)m0 * 32;
    #pragma unroll
    for (int it = 0; it < 8; ++it) {
        int o = tid + it * 256;
        hs[o >> 5][o & 31] = hsrc[o];
    }
    __syncthreads();
    int gg = tid & 31, mg = tid >> 5;
    const u32x4* wt = (const u32x4*)w1T;
    float acc[8][8];
    #pragma unroll
    for (int i = 0; i < 8; ++i)
        #pragma unroll
        for (int r = 0; r < 8; ++r) acc[i][r] = 0.0f;
    for (int k8 = 0; k8 < 32; ++k8) {
        u32x4 w[8], h[8];
        #pragma unroll
        for (int i = 0; i < 8; ++i) w[i] = wt[(size_t)k8 * 256 + gg + 32 * i];
        #pragma unroll
        for (int r = 0; r < 8; ++r) h[r] = hs[mg * 8 + r][k8];
        #pragma unroll
        for (int i = 0; i < 8; ++i)
            #pragma unroll
            for (int r = 0; r < 8; ++r)
                acc[i][r] = dot_u4(w[i], h[r], acc[i][r]);
    }
    float pv[8];
    #pragma unroll
    for (int r = 0; r < 8; ++r) pv[r] = 0.0f;
    #pragma unroll
    for (int i = 0; i < 8; ++i) {
        int g = gg + 32 * i;
        float bias = b1[g], w2g = w2[g];
        #pragma unroll
        for (int r = 0; r < 8; ++r)
            pv[r] += w2g * fmaxf(acc[i][r] + bias, 0.0f);
    }
    #pragma unroll
    for (int r = 0; r < 8; ++r) {
        pv[r] += __shfl_xor(pv[r], 1, 64);
        pv[r] += __shfl_xor(pv[r], 2, 64);
        pv[r] += __shfl_xor(pv[r], 4, 64);
        pv[r] += __shfl_xor(pv[r], 8, 64);
        pv[r] += __shfl_xor(pv[r], 16, 64);
    }
    if (gg == 0) {
        #pragma unroll
        for (int r = 0; r < 8; ++r) red[mg][r] = pv[r];
    }
    __syncthreads();
    if (tid < 64) {
        int m = m0 + tid;
        float v = fmaxf(red[tid >> 3][tid & 7] + b2[0], 0.0f);
        int b = m >> lgC, tl = m & (C - 1);
        out[(size_t)b * T_ + t0 + tl] = v;
    }
}

// ---------- GRU recurrence: 256 threads, thread j owns hidden unit j ----------
// Full K per thread: rows {j, j+256, j+512} of WhhT = 96 u32x4 = 384 VGPRs.
// 1 wave/SIMD (waves_per_eu(1,1)) -> 512-VGPR budget -> no spill incentive.
// h broadcast via LDS (uniform-address reads, conflict-free); one barrier/step.
__device__ __forceinline__ void rec_body(const uint32_t* __restrict__ whhT,
        const float* __restrict__ bhh, const float* __restrict__ xg,
        f16* __restrict__ hout, float* __restrict__ state,
        int b, int C, char* smem) {
    u32x4 (*hq)[32] = (u32x4(*)[32])smem; // [2][32] u32x4 = 1 KB, double-buffered h
    int j = threadIdx.x;

    const u32x4* wu = (const u32x4*)whhT;
    u32x4 W0[32], W1[32], W2[32];          // k-major: coalesced preload
    #pragma unroll
    for (int k8 = 0; k8 < 32; ++k8) {
        W0[k8] = wu[(size_t)k8 * 768 + j];
        W1[k8] = wu[(size_t)k8 * 768 + 256 + j];
        W2[k8] = wu[(size_t)k8 * 768 + 512 + j];
    }

    float h_old = state[b * 256 + j];
    float bhr = bhh[j], bhz = bhh[256 + j], bhn = bhh[512 + j];
    ((f16*)&hq[0][0])[j] = (f16)h_old;
    __syncthreads();

    const float* xgt = xg + (size_t)b * C * G_;
    f16* hob = hout + (size_t)b * C * H_;

    for (int tl = 0; tl < C; ++tl) {
        int p = tl & 1;
        // issue input-gate loads early; consumed after the dots
        float xr = xgt[j], xz = xgt[256 + j], xn = xgt[512 + j];

        float aR = 0.0f, aZ = 0.0f, aN = 0.0f;
        #pragma unroll
        for (int k8 = 0; k8 < 32; ++k8) {
            u32x4 hv = hq[p][k8];          // uniform address -> broadcast
            aR = dot_u4(W0[k8], hv, aR);
            aZ = dot_u4(W1[k8], hv, aZ);
            aN = dot_u4(W2[k8], hv, aN);
        }
        float r = sigmoid_f(xr + aR + bhr);
        float z = sigmoid_f(xz + aZ + bhz);
        float n = tanh_f(xn + r * (aN + bhn));
        h_old = z * (h_old - n) + n;       // (1-z)*n + z*h
        f16 hh = (f16)h_old;
        hob[(size_t)tl * H_ + j] = hh;
        ((f16*)&hq[p ^ 1][0])[j] = hh;
        __syncthreads();
        xgt += G_;
    }
    state[b * 256 + j] = h_old;
}

// =======================================================================
// fused dispatch: blocks [0,64) rec0(i) | [64,128) rec1(i-1) |
//                 [128,128+C) xg0(i+1) | [128+C,128+2C) regressor(i-2)
// 256 threads; waves_per_eu(1,1) -> 512-VGPR budget for the rec role.
// =======================================================================
__global__ __launch_bounds__(256)
__attribute__((amdgpu_waves_per_eu(1, 1)))
void fused_step(int i, int nC, int C, int lgC,
        const float* __restrict__ x,
        const float* __restrict__ wih0, const float* __restrict__ bih0,
        const uint32_t* __restrict__ whh0T, const float* __restrict__ bhh0,
        const uint32_t* __restrict__ whh1T, const float* __restrict__ bhh1,
        const uint32_t* __restrict__ w1T, const float* __restrict__ b1,
        const float* __restrict__ w2, const float* __restrict__ b2,
        float* __restrict__ xg0a, float* __restrict__ xg0b,
        float* __restrict__ xg1b,
        f16* __restrict__ h1,
        f16* __restrict__ h2a, f16* __restrict__ h2b,
        float* __restrict__ st0, float* __restrict__ st1,
        float* __restrict__ out) {
    __shared__ __align__(16) char smem[33024];
    int blk = blockIdx.x;
    if (blk < 128) {
        const uint32_t* whh; const float* bhh; const float* xgp; f16* hout; float* st; int b;
        if (blk < 64) {
            if (i >= nC) return;
            whh = whh0T; bhh = bhh0; xgp = (i & 1) ? xg0b : xg0a;
            hout = h1; st = st0; b = blk;
        } else {
            if (i < 1) return;
            whh = whh1T; bhh = bhh1; xgp = xg1b;
            hout = ((i - 1) & 1) ? h2b : h2a; st = st1; b = blk - 64;
        }
        rec_body(whh, bhh, xgp, hout, st, b, C, smem);
    } else if (blk < 128 + C) {
        if (i + 1 >= nC) return;
        xg0_body(x, wih0, bih0, ((i + 1) & 1) ? xg0b : xg0a, (i + 1) * C, C, blk - 128, smem);
    } else {
        if (i < 2) return;
        reg_body((i & 1) ? h2b : h2a, w1T, b1, w2, b2, out, (i - 2) * C, C, lgC,
                 blk - 128 - C, smem);
    }
}

// ---------- standalone wrappers ----------
__global__ __launch_bounds__(256)
__attribute__((amdgpu_waves_per_eu(1, 1)))
void rec_stand(const uint32_t* __restrict__ whhT, const float* __restrict__ bhh,
        const float* __restrict__ xg, f16* __restrict__ hout,
        float* __restrict__ state, int C) {
    __shared__ __align__(16) char smem[1024];
    rec_body(whhT, bhh, xg, hout, state, blockIdx.x, C, smem);
}

__global__ __launch_bounds__(256) void xg0_stand(const float* __restrict__ x,
        const float* __restrict__ wih0, const float* __restrict__ bih0,
        float* __restrict__ xg, int t0, int C) {
    __shared__ __align__(16) char smem[4096];
    xg0_body(x, wih0, bih0, xg, t0, C, blockIdx.x, smem);
}

__global__ __launch_bounds__(256) void reg_stand(const f16* __restrict__ h2,
        const uint32_t* __restrict__ w1T, const float* __restrict__ b1,
        const float* __restrict__ w2, const float* __restrict__ b2,
        float* __restrict__ out, int t0, int C, int lgC) {
    __shared__ __align__(16) char smem[33024];
    reg_body(h2, w1T, b1, w2, b2, out, t0, C, lgC, blockIdx.x, smem);
}

// ---------- xg1 = bih1 + h1 @ Wih1^T  (standalone, on critical path) ----------
__global__ __launch_bounds__(256) void xg1_kernel(const f16* __restrict__ h1,
        const uint32_t* __restrict__ wih1T, const float* __restrict__ bih1,
        float* __restrict__ xg, int C) {
    __shared__ u32x4 hs[64][32]; // 32 KB
    int tid = threadIdx.x;
    int m0 = blockIdx.x * 64;
    int gbase = blockIdx.y * 256;
    const u32x4* hsrc = (const u32x4*)h1 + (size_t)m0 * 32;
    #pragma unroll
    for (int it = 0; it < 8; ++it) {
        int o = tid + it * 256;
        hs[o >> 5][o & 31] = hsrc[o];
    }
    __syncthreads();
    int gg = tid & 31, mg = tid >> 5;
    const u32x4* wt = (const u32x4*)wih1T;
    float acc[8][8];
    #pragma unroll
    for (int i = 0; i < 8; ++i)
        #pragma unroll
        for (int r = 0; r < 8; ++r) acc[i][r] = 0.0f;
    for (int k8 = 0; k8 < 32; ++k8) {
        u32x4 w[8], h[8];
        #pragma unroll
        for (int i = 0; i < 8; ++i) w[i] = wt[(size_t)k8 * 768 + gbase + gg + 32 * i];
        #pragma unroll
        for (int r = 0; r < 8; ++r) h[r] = hs[mg * 8 + r][k8];
        #pragma unroll
        for (int i = 0; i < 8; ++i)
            #pragma unroll
            for (int r = 0; r < 8; ++r)
                acc[i][r] = dot_u4(w[i], h[r], acc[i][r]);
    }
    #pragma unroll
    for (int i = 0; i < 8; ++i) {
        int g = gbase + gg + 32 * i;
        float bias = bih1[g];
        #pragma unroll
        for (int r = 0; r < 8; ++r)
            xg[(size_t)(m0 + mg * 8 + r) * G_ + g] = acc[i][r] + bias;
    }
}

// ---------- host ----------
extern "C" void kernel_launch(void* const* d_in, const int* in_sizes, int n_in,
                              void* d_out, int out_size, void* d_ws, size_t ws_size,
                              hipStream_t stream) {
    const float* x    = (const float*)d_in[0];
    const float* Wih0 = (const float*)d_in[1];
    const float* Whh0 = (const float*)d_in[2];
    const float* bih0 = (const float*)d_in[3];
    const float* bhh0 = (const float*)d_in[4];
    const float* Wih1 = (const float*)d_in[5];
    const float* Whh1 = (const float*)d_in[6];
    const float* bih1 = (const float*)d_in[7];
    const float* bhh1 = (const float*)d_in[8];
    const float* W1   = (const float*)d_in[9];
    const float* b1   = (const float*)d_in[10];
    const float* W2   = (const float*)d_in[11];
    const float* b2   = (const float*)d_in[12];
    float* out = (float*)d_out;

    char* ws = (char*)d_ws;
    uint32_t* wcvt = (uint32_t*)ws;             // 327680 dwords
    const uint32_t* whh0T = wcvt;
    const uint32_t* whh1T = wcvt + 98304;
    const uint32_t* wih1T = wcvt + 196608;
    const uint32_t* w1T   = wcvt + 294912;
    float* state0 = (float*)(ws + 1310720);
    float* state1 = (float*)(ws + 1310720 + 65536);
    size_t fixed = 1310720 + 2 * 65536;

    // per-chunk: xg0 x2 + xg1 (196608C each) + h1 (32768C) + h2 x2 (32768C each)
    int C = 512;
    while (C > 32 && fixed + (size_t)C * 688128 > ws_size) C >>= 1;
    int lgC = 0; while ((1 << lgC) < C) lgC++;
    int nC = T_ / C;

    char* p = ws + fixed;
    float* xg0_buf[2];
    xg0_buf[0] = (float*)p;  p += (size_t)C * 196608;
    xg0_buf[1] = (float*)p;  p += (size_t)C * 196608;
    float* xg1_buf = (float*)p; p += (size_t)C * 196608;
    f16* h1_buf = (f16*)p;   p += (size_t)C * 32768;
    f16* h2_buf[2];
    h2_buf[0] = (f16*)p;     p += (size_t)C * 32768;
    h2_buf[1] = (f16*)p;

    cvt_weights<<<1280, 256, 0, stream>>>(Whh0, Whh1, Wih1, W1, wcvt);
    hipMemsetAsync(state0, 0, 2 * 65536, stream);
    xg0_stand<<<C, 256, 0, stream>>>(x, Wih0, bih0, xg0_buf[0], 0, C);

    for (int i = 0; i <= nC; ++i) {
        fused_step<<<128 + 2 * C, 256, 0, stream>>>(i, nC, C, lgC,
            x, Wih0, bih0, whh0T, bhh0, whh1T, bhh1, w1T, b1, W2, b2,
            xg0_buf[0], xg0_buf[1], xg1_buf, h1_buf, h2_buf[0], h2_buf[1],
            state0, state1, out);
        if (i < nC)
            xg1_kernel<<<dim3(C, 3), 256, 0, stream>>>(h1_buf, wih1T, bih1, xg1_buf, C);
    }
    reg_stand<<<C, 256, 0, stream>>>(h2_buf[(nC - 1) & 1], w1T, b1, W2, b2, out,
                                     (nC - 1) * C, C, lgC);
}

// Round 9
// 3633.923 us; speedup vs baseline: 1.7481x; 1.7481x over previous
//
#include <hip/hip_runtime.h>
#include <hip/hip_fp16.h>
#include <stdint.h>

#define B_ 64
#define T_ 2048
#define I_ 16
#define H_ 256
#define G_ 768   // 3*H

// dynamic LDS for fused_step: n-gate 131072 + hq 1024
#define REC_SMEM 132096

typedef _Float16 f16;
typedef _Float16 half2_t __attribute__((ext_vector_type(2)));
typedef uint32_t u32x4 __attribute__((ext_vector_type(4)));

// ---------- fast math helpers ----------
__device__ __forceinline__ float fast_rcp(float x) {
#if __has_builtin(__builtin_amdgcn_rcpf)
    return __builtin_amdgcn_rcpf(x);
#else
    return 1.0f / x;
#endif
}
__device__ __forceinline__ float sigmoid_f(float x) {
    return fast_rcp(1.0f + __expf(-x));
}
__device__ __forceinline__ float tanh_f(float x) {
    float e = __expf(2.0f * x);
    return 1.0f - 2.0f * fast_rcp(e + 1.0f);
}

__device__ __forceinline__ float fdot2(uint32_t a, uint32_t b, float c) {
#if __has_builtin(__builtin_amdgcn_fdot2)
    return __builtin_amdgcn_fdot2(__builtin_bit_cast(half2_t, a),
                                  __builtin_bit_cast(half2_t, b), c, false);
#else
    half2_t ha = __builtin_bit_cast(half2_t, a), hb = __builtin_bit_cast(half2_t, b);
    return c + (float)ha.x * (float)hb.x + (float)ha.y * (float)hb.y;
#endif
}
__device__ __forceinline__ float dot_u4(u32x4 w, u32x4 h, float acc) {
    acc = fdot2(w.x, h.x, acc);
    acc = fdot2(w.y, h.y, acc);
    acc = fdot2(w.z, h.z, acc);
    acc = fdot2(w.w, h.w, acc);
    return acc;
}

// ---------- weight fp32 -> packed fp16 conversion ----------
// u32x4-unit layout per Whh layer (layer base = layer*24576 u32x4):
//   planes [0,16384):  stream r,z thread-major. plane u<16 = r, u in [16,32) = z.
//     u32x4 at u*512 + tid  (tid = 2j+hf) = row (gate*256+j), halves hf*128+(u%16)*8 ..+8
//   [16384,24576): n-gate row-major: idx l: row 512+(l>>5), halves (l&31)*8 ..+8
// then (dword offsets as before):
//   [196608,294912) Wih1T k-major | [294912,327680) W1T k-major
__global__ __launch_bounds__(256) void cvt_weights(const float* __restrict__ whh0,
                                                   const float* __restrict__ whh1,
                                                   const float* __restrict__ wih1,
                                                   const float* __restrict__ w1,
                                                   uint32_t* __restrict__ out) {
    int idx = blockIdx.x * 256 + threadIdx.x;
    if (idx >= 327680) return;
    const float* s;
    if (idx < 196608) {
        const float* w = (idx < 98304) ? whh0 : whh1;
        int lidx = (idx < 98304) ? idx : idx - 98304;
        int u4 = lidx >> 2, d = lidx & 3;
        int row, halfoff;
        if (u4 < 16384) {
            int u = u4 >> 9, tid = u4 & 511;
            int j = tid >> 1, hf = tid & 1;
            row = (u < 16 ? 0 : 256) + j;
            halfoff = hf * 128 + (u & 15) * 8;
        } else {
            int l2 = u4 - 16384;
            row = 512 + (l2 >> 5);
            halfoff = (l2 & 31) * 8;
        }
        s = w + (size_t)row * 256 + halfoff + d * 2;
    } else if (idx < 294912) {
        int local = idx - 196608;
        int u4 = local >> 2, d = local & 3;
        int k8 = u4 / 768, g = u4 - k8 * 768;
        s = wih1 + (size_t)g * 256 + k8 * 8 + d * 2;
    } else {
        int local = idx - 294912;
        int u4 = local >> 2, d = local & 3;
        int k8 = u4 >> 8, g = u4 & 255;
        s = w1 + (size_t)g * 256 + k8 * 8 + d * 2;
    }
    half2_t h;
    h.x = (f16)s[0];
    h.y = (f16)s[1];
    out[idx] = __builtin_bit_cast(uint32_t, h);
}

// =======================================================================
// role bodies
// =======================================================================

// ---------- xg0 = bih0 + x @ Wih0^T (K=16, fp32), 512 threads ----------
__device__ __forceinline__ void xg0_body(const float* __restrict__ x,
        const float* __restrict__ wih0, const float* __restrict__ bih0,
        float* __restrict__ xg, int t0, int C, int blk, char* smem) {
    float (*xs)[16] = (float(*)[16])smem;
    int tid = threadIdx.x;
    int m0 = blk * 64;
    if (tid < 256) {
        int r = tid >> 2, c4 = (tid & 3) * 4;
        int m = m0 + r;
        int b = m / C, tl = m - b * C;
        float4 v = *(const float4*)(x + (size_t)(b * T_ + t0 + tl) * I_ + c4);
        *(float4*)&xs[r][c4] = v;
    }
    __syncthreads();
    for (int g = tid; g < G_; g += 512) {
        const float4* wr = (const float4*)(wih0 + (size_t)g * I_);
        float4 w0 = wr[0], w1 = wr[1], w2 = wr[2], w3 = wr[3];
        float bias = bih0[g];
        float* outp = xg + (size_t)m0 * G_ + g;
        for (int m = 0; m < 64; ++m) {
            const float4* xr4 = (const float4*)xs[m];
            float4 a0 = xr4[0], a1 = xr4[1], a2 = xr4[2], a3 = xr4[3];
            float acc = bias;
            acc += a0.x*w0.x + a0.y*w0.y + a0.z*w0.z + a0.w*w0.w;
            acc += a1.x*w1.x + a1.y*w1.y + a1.z*w1.z + a1.w*w1.w;
            acc += a2.x*w2.x + a2.y*w2.y + a2.z*w2.z + a2.w*w2.w;
            acc += a3.x*w3.x + a3.y*w3.y + a3.z*w3.z + a3.w*w3.w;
            outp[(size_t)m * G_] = acc;
        }
    }
}

// ---------- regressor, 512 threads, 8g x 4m register tile ----------
__device__ __forceinline__ void reg_body(const f16* __restrict__ h2,
        const uint32_t* __restrict__ w1T, const float* __restrict__ b1,
        const float* __restrict__ w2, const float* __restrict__ b2,
        float* __restrict__ out, int t0, int C, int lgC, int blk, char* smem) {
    u32x4 (*hs)[32] = (u32x4(*)[32])smem;            // 32 KB
    float (*red)[4] = (float(*)[4])(smem + 32768);   // [16][4]
    int tid = threadIdx.x;
    int m0 = blk * 64;
    const u32x4* hsrc = (const u32x4*)h2 + (size_t)m0 * 32;
    #pragma unroll
    for (int it = 0; it < 4; ++it) {
        int o = tid + it * 512;
        hs[o >> 5][o & 31] = hsrc[o];
    }
    __syncthreads();
    int gg = tid & 31, mg = tid >> 5;
    const u32x4* wt = (const u32x4*)w1T;
    float acc[8][4];
    #pragma unroll
    for (int i = 0; i < 8; ++i)
        #pragma unroll
        for (int r = 0; r < 4; ++r) acc[i][r] = 0.0f;
    for (int k8 = 0; k8 < 32; ++k8) {
        u32x4 w[8], h[4];
        #pragma unroll
        for (int i = 0; i < 8; ++i) w[i] = wt[(size_t)k8 * 256 + gg + 32 * i];
        #pragma unroll
        for (int r = 0; r < 4; ++r) h[r] = hs[mg * 4 + r][k8];
        #pragma unroll
        for (int i = 0; i < 8; ++i)
            #pragma unroll
            for (int r = 0; r < 4; ++r)
                acc[i][r] = dot_u4(w[i], h[r], acc[i][r]);
    }
    float pv[4] = {0, 0, 0, 0};
    #pragma unroll
    for (int i = 0; i < 8; ++i) {
        int g = gg + 32 * i;
        float bias = b1[g], w2g = w2[g];
        #pragma unroll
        for (int r = 0; r < 4; ++r)
            pv[r] += w2g * fmaxf(acc[i][r] + bias, 0.0f);
    }
    #pragma unroll
    for (int r = 0; r < 4; ++r) {
        pv[r] += __shfl_xor(pv[r], 1, 64);
        pv[r] += __shfl_xor(pv[r], 2, 64);
        pv[r] += __shfl_xor(pv[r], 4, 64);
        pv[r] += __shfl_xor(pv[r], 8, 64);
        pv[r] += __shfl_xor(pv[r], 16, 64);
    }
    if (gg == 0) {
        #pragma unroll
        for (int r = 0; r < 4; ++r) red[mg][r] = pv[r];
    }
    __syncthreads();
    if (tid < 64) {
        int m = m0 + tid;
        float v = fmaxf(red[tid >> 2][tid & 3] + b2[0], 0.0f);
        int b = m >> lgC, tl = m & (C - 1);
        out[(size_t)b * T_ + t0 + tl] = v;
    }
}

// ---------- GRU recurrence: n-gate LDS-resident (swizzled), r/z streamed ----------
// 512 threads: tid = 2j+hf; j = hidden unit, hf = K-half.
// Per step: 32 coalesced u32x4 stream loads (r,z) + 16 swizzled LDS reads (n)
//           + 16 broadcast LDS reads (h).
__device__ __forceinline__ void rec_body(const uint32_t* __restrict__ whh,
        const float* __restrict__ bhh, const float* __restrict__ xg,
        f16* __restrict__ hout, float* __restrict__ state,
        int b, int C, char* smem) {
    int tid = threadIdx.x;
    int j = tid >> 1, hf = tid & 1;
    const u32x4* wb = (const u32x4*)whh;          // layer base, u32x4 units
    u32x4 (*hq)[32] = (u32x4(*)[32])(smem + 131072);

    // stage n-gate into LDS with T2 XOR swizzle (row-major [256][512B])
    const u32x4* n_rm = wb + 16384;
    #pragma unroll
    for (int it = 0; it < 16; ++it) {
        int idx = it * 512 + tid;
        int row = idx >> 5, u = idx & 31;
        u32x4 v = n_rm[idx];
        *(u32x4*)(smem + row * 512 + ((u * 16) ^ ((row & 15) << 4))) = v;
    }

    float h_old = 0.0f, bhr = 0.0f, bhz = 0.0f, bhn = 0.0f;
    if (hf == 0) {
        h_old = state[b * 256 + j];
        bhr = bhh[j]; bhz = bhh[256 + j]; bhn = bhh[512 + j];
        ((f16*)&hq[0][0])[j] = (f16)h_old;
    }
    __syncthreads();

    const float* xgt = xg + (size_t)b * C * G_;
    f16* hob = hout + (size_t)b * C * H_;
    const char* nrow = smem + j * 512;
    int jsw = (j & 15) << 4;

    for (int tl = 0; tl < C; ++tl) {
        int p = tl & 1;
        float xr = 0, xz = 0, xn = 0;
        if (hf == 0) { xr = xgt[j]; xz = xgt[256 + j]; xn = xgt[512 + j]; }

        const u32x4* hp = &hq[p][hf * 16];
        float aR = 0.0f, aZ = 0.0f, aN = 0.0f;
        #pragma unroll
        for (int u = 0; u < 16; ++u) {
            u32x4 hv = hp[u];                                  // broadcast read
            u32x4 wr = wb[u * 512 + tid];                      // coalesced stream
            u32x4 wz = wb[(16 + u) * 512 + tid];               // coalesced stream
            u32x4 wn = *(const u32x4*)(nrow + ((hf * 256 + u * 16) ^ jsw)); // LDS
            aR = dot_u4(wr, hv, aR);
            aZ = dot_u4(wz, hv, aZ);
            aN = dot_u4(wn, hv, aN);
        }
        // combine the two K-halves (lanes 2j / 2j+1)
        aR += __shfl_xor(aR, 1, 64);
        aZ += __shfl_xor(aZ, 1, 64);
        aN += __shfl_xor(aN, 1, 64);

        if (hf == 0) {
            float r = sigmoid_f(xr + aR + bhr);
            float z = sigmoid_f(xz + aZ + bhz);
            float n = tanh_f(xn + r * (aN + bhn));
            h_old = z * (h_old - n) + n;   // (1-z)*n + z*h
            f16 hh = (f16)h_old;
            hob[(size_t)tl * H_ + j] = hh;
            ((f16*)&hq[p ^ 1][0])[j] = hh;
        }
        __syncthreads();
        xgt += G_;
    }
    if (hf == 0) state[b * 256 + j] = h_old;
}

// =======================================================================
// fused dispatch: blocks [0,64) rec0(i) | [64,128) rec1(i-1) |
//                 [128,128+C) xg0(i+1) | [128+C,128+2C) regressor(i-2)
// dynamic LDS = REC_SMEM (132 KB) -> 1 block/CU, 2 waves/SIMD for rec.
// =======================================================================
__global__ __launch_bounds__(512) void fused_step(int i, int nC, int C, int lgC,
        const float* __restrict__ x,
        const float* __restrict__ wih0, const float* __restrict__ bih0,
        const uint32_t* __restrict__ whh0, const float* __restrict__ bhh0,
        const uint32_t* __restrict__ whh1, const float* __restrict__ bhh1,
        const uint32_t* __restrict__ w1T, const float* __restrict__ b1,
        const float* __restrict__ w2, const float* __restrict__ b2,
        float* __restrict__ xg0a, float* __restrict__ xg0b,
        float* __restrict__ xg1b,
        f16* __restrict__ h1,
        f16* __restrict__ h2a, f16* __restrict__ h2b,
        float* __restrict__ st0, float* __restrict__ st1,
        float* __restrict__ out) {
    extern __shared__ __align__(16) char smem[];
    int blk = blockIdx.x;
    if (blk < 128) {
        const uint32_t* whh; const float* bhh; const float* xgp; f16* hout; float* st; int b;
        if (blk < 64) {
            if (i >= nC) return;
            whh = whh0; bhh = bhh0; xgp = (i & 1) ? xg0b : xg0a;
            hout = h1; st = st0; b = blk;
        } else {
            if (i < 1) return;
            whh = whh1; bhh = bhh1; xgp = xg1b;
            hout = ((i - 1) & 1) ? h2b : h2a; st = st1; b = blk - 64;
        }
        rec_body(whh, bhh, xgp, hout, st, b, C, smem);
    } else if (blk < 128 + C) {
        if (i + 1 >= nC) return;
        xg0_body(x, wih0, bih0, ((i + 1) & 1) ? xg0b : xg0a, (i + 1) * C, C, blk - 128, smem);
    } else {
        if (i < 2) return;
        reg_body((i & 1) ? h2b : h2a, w1T, b1, w2, b2, out, (i - 2) * C, C, lgC,
                 blk - 128 - C, smem);
    }
}

// ---------- standalone wrappers ----------
__global__ __launch_bounds__(512) void xg0_stand(const float* __restrict__ x,
        const float* __restrict__ wih0, const float* __restrict__ bih0,
        float* __restrict__ xg, int t0, int C) {
    __shared__ __align__(16) char smem[4096];
    xg0_body(x, wih0, bih0, xg, t0, C, blockIdx.x, smem);
}

__global__ __launch_bounds__(512) void reg_stand(const f16* __restrict__ h2,
        const uint32_t* __restrict__ w1T, const float* __restrict__ b1,
        const float* __restrict__ w2, const float* __restrict__ b2,
        float* __restrict__ out, int t0, int C, int lgC) {
    __shared__ __align__(16) char smem[33024];
    reg_body(h2, w1T, b1, w2, b2, out, t0, C, lgC, blockIdx.x, smem);
}

// ---------- xg1 = bih1 + h1 @ Wih1^T  (standalone, on critical path) ----------
__global__ __launch_bounds__(256) void xg1_kernel(const f16* __restrict__ h1,
        const uint32_t* __restrict__ wih1T, const float* __restrict__ bih1,
        float* __restrict__ xg, int C) {
    __shared__ u32x4 hs[64][32]; // 32 KB
    int tid = threadIdx.x;
    int m0 = blockIdx.x * 64;
    int gbase = blockIdx.y * 256;
    const u32x4* hsrc = (const u32x4*)h1 + (size_t)m0 * 32;
    #pragma unroll
    for (int it = 0; it < 8; ++it) {
        int o = tid + it * 256;
        hs[o >> 5][o & 31] = hsrc[o];
    }
    __syncthreads();
    int gg = tid & 31, mg = tid >> 5;
    const u32x4* wt = (const u32x4*)wih1T;
    float acc[8][8];
    #pragma unroll
    for (int i = 0; i < 8; ++i)
        #pragma unroll
        for (int r = 0; r < 8; ++r) acc[i][r] = 0.0f;
    for (int k8 = 0; k8 < 32; ++k8) {
        u32x4 w[8], h[8];
        #pragma unroll
        for (int i = 0; i < 8; ++i) w[i] = wt[(size_t)k8 * 768 + gbase + gg + 32 * i];
        #pragma unroll
        for (int r = 0; r < 8; ++r) h[r] = hs[mg * 8 + r][k8];
        #pragma unroll
        for (int i = 0; i < 8; ++i)
            #pragma unroll
            for (int r = 0; r < 8; ++r)
                acc[i][r] = dot_u4(w[i], h[r], acc[i][r]);
    }
    #pragma unroll
    for (int i = 0; i < 8; ++i) {
        int g = gbase + gg + 32 * i;
        float bias = bih1[g];
        #pragma unroll
        for (int r = 0; r < 8; ++r)
            xg[(size_t)(m0 + mg * 8 + r) * G_ + g] = acc[i][r] + bias;
    }
}

// ---------- host ----------
extern "C" void kernel_launch(void* const* d_in, const int* in_sizes, int n_in,
                              void* d_out, int out_size, void* d_ws, size_t ws_size,
                              hipStream_t stream) {
    const float* x    = (const float*)d_in[0];
    const float* Wih0 = (const float*)d_in[1];
    const float* Whh0 = (const float*)d_in[2];
    const float* bih0 = (const float*)d_in[3];
    const float* bhh0 = (const float*)d_in[4];
    const float* Wih1 = (const float*)d_in[5];
    const float* Whh1 = (const float*)d_in[6];
    const float* bih1 = (const float*)d_in[7];
    const float* bhh1 = (const float*)d_in[8];
    const float* W1   = (const float*)d_in[9];
    const float* b1   = (const float*)d_in[10];
    const float* W2   = (const float*)d_in[11];
    const float* b2   = (const float*)d_in[12];
    float* out = (float*)d_out;

    // allow 132 KB dynamic LDS for fused_step (idempotent, capture-safe)
    hipFuncSetAttribute(reinterpret_cast<const void*>(fused_step),
                        hipFuncAttributeMaxDynamicSharedMemorySize, REC_SMEM);

    char* ws = (char*)d_ws;
    uint32_t* wcvt = (uint32_t*)ws;             // 327680 dwords
    const uint32_t* whh0c = wcvt;
    const uint32_t* whh1c = wcvt + 98304;
    const uint32_t* wih1T = wcvt + 196608;
    const uint32_t* w1T   = wcvt + 294912;
    float* state0 = (float*)(ws + 1310720);
    float* state1 = (float*)(ws + 1310720 + 65536);
    size_t fixed = 1310720 + 2 * 65536;

    // per-chunk: xg0 x2 + xg1 (196608C each) + h1 (32768C) + h2 x2 (32768C each)
    int C = 512;
    while (C > 32 && fixed + (size_t)C * 688128 > ws_size) C >>= 1;
    int lgC = 0; while ((1 << lgC) < C) lgC++;
    int nC = T_ / C;

    char* p = ws + fixed;
    float* xg0_buf[2];
    xg0_buf[0] = (float*)p;  p += (size_t)C * 196608;
    xg0_buf[1] = (float*)p;  p += (size_t)C * 196608;
    float* xg1_buf = (float*)p; p += (size_t)C * 196608;
    f16* h1_buf = (f16*)p;   p += (size_t)C * 32768;
    f16* h2_buf[2];
    h2_buf[0] = (f16*)p;     p += (size_t)C * 32768;
    h2_buf[1] = (f16*)p;

    cvt_weights<<<1280, 256, 0, stream>>>(Whh0, Whh1, Wih1, W1, wcvt);
    hipMemsetAsync(state0, 0, 2 * 65536, stream);
    xg0_stand<<<C, 512, 0, stream>>>(x, Wih0, bih0, xg0_buf[0], 0, C);

    for (int i = 0; i <= nC; ++i) {
        fused_step<<<128 + 2 * C, 512, REC_SMEM, stream>>>(i, nC, C, lgC,
            x, Wih0, bih0, whh0c, bhh0, whh1c, bhh1, w1T, b1, W2, b2,
            xg0_buf[0], xg0_buf[1], xg1_buf, h1_buf, h2_buf[0], h2_buf[1],
            state0, state1, out);
        if (i < nC)
            xg1_kernel<<<dim3(C, 3), 256, 0, stream>>>(h1_buf, wih1T, bih1, xg1_buf, C);
    }
    reg_stand<<<C, 512, 0, stream>>>(h2_buf[(nC - 1) & 1], w1T, b1, W2, b2, out,
                                     (nC - 1) * C, C, lgC);
}

// Round 10
// 3021.821 us; speedup vs baseline: 2.1022x; 1.2026x over previous
//
#include <hip/hip_runtime.h>
#include <hip/hip_fp16.h>
#include <stdint.h>

#define B_ 64
#define T_ 2048
#define I_ 16
#define H_ 256
#define G_ 768   // 3*H

// dynamic LDS: 16 n-planes thread-major (131072) + hq[2][2][17] u32x4 (1088)
#define REC_SMEM 132160

typedef _Float16 f16;
typedef _Float16 half2_t __attribute__((ext_vector_type(2)));
typedef uint32_t u32x4 __attribute__((ext_vector_type(4)));

// ---------- fast math helpers ----------
__device__ __forceinline__ float fast_rcp(float x) {
#if __has_builtin(__builtin_amdgcn_rcpf)
    return __builtin_amdgcn_rcpf(x);
#else
    return 1.0f / x;
#endif
}
__device__ __forceinline__ float sigmoid_f(float x) {
    return fast_rcp(1.0f + __expf(-x));
}
__device__ __forceinline__ float tanh_f(float x) {
    float e = __expf(2.0f * x);
    return 1.0f - 2.0f * fast_rcp(e + 1.0f);
}

__device__ __forceinline__ float fdot2(uint32_t a, uint32_t b, float c) {
#if __has_builtin(__builtin_amdgcn_fdot2)
    return __builtin_amdgcn_fdot2(__builtin_bit_cast(half2_t, a),
                                  __builtin_bit_cast(half2_t, b), c, false);
#else
    half2_t ha = __builtin_bit_cast(half2_t, a), hb = __builtin_bit_cast(half2_t, b);
    return c + (float)ha.x * (float)hb.x + (float)ha.y * (float)hb.y;
#endif
}
__device__ __forceinline__ float dot_u4(u32x4 w, u32x4 h, float acc) {
    acc = fdot2(w.x, h.x, acc);
    acc = fdot2(w.y, h.y, acc);
    acc = fdot2(w.z, h.z, acc);
    acc = fdot2(w.w, h.w, acc);
    return acc;
}

// ---------- weight fp32 -> packed fp16 conversion ----------
// Whh layers (dwords [0,98304) L0, [98304,196608) L1): 48 thread-major planes.
//   u32x4 index within layer: P*512 + tid, P = gate*16+u (r=0,z=1,n=2),
//   tid = 2j+hf -> row = gate*256+j, halves hf*128+u*8 .. +8.
// [196608,294912) Wih1T k-major: u32x4 = k8*768 + g
// [294912,327680) W1T   k-major: u32x4 = k8*256 + g
__global__ __launch_bounds__(256) void cvt_weights(const float* __restrict__ whh0,
                                                   const float* __restrict__ whh1,
                                                   const float* __restrict__ wih1,
                                                   const float* __restrict__ w1,
                                                   uint32_t* __restrict__ out) {
    int idx = blockIdx.x * 256 + threadIdx.x;
    if (idx >= 327680) return;
    const float* s;
    if (idx < 196608) {
        const float* w = (idx < 98304) ? whh0 : whh1;
        int lidx = (idx < 98304) ? idx : idx - 98304;
        int u4 = lidx >> 2, d = lidx & 3;
        int P = u4 >> 9, t = u4 & 511;
        int j = t >> 1, hf = t & 1;
        int gate = P >> 4, u = P & 15;
        int row = gate * 256 + j;
        int halfoff = hf * 128 + u * 8;
        s = w + (size_t)row * 256 + halfoff + d * 2;
    } else if (idx < 294912) {
        int local = idx - 196608;
        int u4 = local >> 2, d = local & 3;
        int k8 = u4 / 768, g = u4 - k8 * 768;
        s = wih1 + (size_t)g * 256 + k8 * 8 + d * 2;
    } else {
        int local = idx - 294912;
        int u4 = local >> 2, d = local & 3;
        int k8 = u4 >> 8, g = u4 & 255;
        s = w1 + (size_t)g * 256 + k8 * 8 + d * 2;
    }
    half2_t h;
    h.x = (f16)s[0];
    h.y = (f16)s[1];
    out[idx] = __builtin_bit_cast(uint32_t, h);
}

// =======================================================================
// role bodies (512 threads each)
// =======================================================================

// ---------- xg0 = bih0 + x @ Wih0^T (K=16, fp32), one 64-row tile ----------
__device__ __forceinline__ void xg0_body(const float* __restrict__ x,
        const float* __restrict__ wih0, const float* __restrict__ bih0,
        float* __restrict__ xg, int t0, int C, int blk, char* smem) {
    float (*xs)[16] = (float(*)[16])smem;
    int tid = threadIdx.x;
    int m0 = blk * 64;
    if (tid < 256) {
        int r = tid >> 2, c4 = (tid & 3) * 4;
        int m = m0 + r;
        int b = m / C, tl = m - b * C;
        float4 v = *(const float4*)(x + (size_t)(b * T_ + t0 + tl) * I_ + c4);
        *(float4*)&xs[r][c4] = v;
    }
    __syncthreads();
    for (int g = tid; g < G_; g += 512) {
        const float4* wr = (const float4*)(wih0 + (size_t)g * I_);
        float4 w0 = wr[0], w1 = wr[1], w2 = wr[2], w3 = wr[3];
        float bias = bih0[g];
        float* outp = xg + (size_t)m0 * G_ + g;
        for (int m = 0; m < 64; ++m) {
            const float4* xr4 = (const float4*)xs[m];
            float4 a0 = xr4[0], a1 = xr4[1], a2 = xr4[2], a3 = xr4[3];
            float acc = bias;
            acc += a0.x*w0.x + a0.y*w0.y + a0.z*w0.z + a0.w*w0.w;
            acc += a1.x*w1.x + a1.y*w1.y + a1.z*w1.z + a1.w*w1.w;
            acc += a2.x*w2.x + a2.y*w2.y + a2.z*w2.z + a2.w*w2.w;
            acc += a3.x*w3.x + a3.y*w3.y + a3.z*w3.z + a3.w*w3.w;
            outp[(size_t)m * G_] = acc;
        }
    }
}

// ---------- xg1 = bih1 + h1 @ Wih1^T, 8g x 4m tile; blk in [0,3C) ----------
__device__ __forceinline__ void xg1_body(const f16* __restrict__ h1,
        const uint32_t* __restrict__ wih1T, const float* __restrict__ bih1,
        float* __restrict__ xg, int C, int lgC, int blk, char* smem) {
    u32x4 (*hs)[32] = (u32x4(*)[32])smem;   // 32 KB
    int tid = threadIdx.x;
    int m0 = (blk & (C - 1)) * 64;
    int gbase = (blk >> lgC) * 256;
    const u32x4* hsrc = (const u32x4*)h1 + (size_t)m0 * 32;
    #pragma unroll
    for (int it = 0; it < 4; ++it) {
        int o = tid + it * 512;
        hs[o >> 5][o & 31] = hsrc[o];
    }
    __syncthreads();
    int gg = tid & 31, mg = tid >> 5;       // mg in [0,16)
    const u32x4* wt = (const u32x4*)wih1T;
    float acc[8][4];
    #pragma unroll
    for (int i = 0; i < 8; ++i)
        #pragma unroll
        for (int r = 0; r < 4; ++r) acc[i][r] = 0.0f;
    for (int k8 = 0; k8 < 32; ++k8) {
        u32x4 w[8], h[4];
        #pragma unroll
        for (int i = 0; i < 8; ++i) w[i] = wt[(size_t)k8 * 768 + gbase + gg + 32 * i];
        #pragma unroll
        for (int r = 0; r < 4; ++r) h[r] = hs[mg * 4 + r][k8];
        #pragma unroll
        for (int i = 0; i < 8; ++i)
            #pragma unroll
            for (int r = 0; r < 4; ++r)
                acc[i][r] = dot_u4(w[i], h[r], acc[i][r]);
    }
    #pragma unroll
    for (int i = 0; i < 8; ++i) {
        int g = gbase + gg + 32 * i;
        float bias = bih1[g];
        #pragma unroll
        for (int r = 0; r < 4; ++r)
            xg[(size_t)(m0 + mg * 4 + r) * G_ + g] = acc[i][r] + bias;
    }
}

// ---------- regressor, 8g x 4m tile ----------
__device__ __forceinline__ void reg_body(const f16* __restrict__ h2,
        const uint32_t* __restrict__ w1T, const float* __restrict__ b1,
        const float* __restrict__ w2, const float* __restrict__ b2,
        float* __restrict__ out, int t0, int C, int lgC, int blk, char* smem) {
    u32x4 (*hs)[32] = (u32x4(*)[32])smem;            // 32 KB
    float (*red)[4] = (float(*)[4])(smem + 32768);   // [16][4]
    int tid = threadIdx.x;
    int m0 = blk * 64;
    const u32x4* hsrc = (const u32x4*)h2 + (size_t)m0 * 32;
    #pragma unroll
    for (int it = 0; it < 4; ++it) {
        int o = tid + it * 512;
        hs[o >> 5][o & 31] = hsrc[o];
    }
    __syncthreads();
    int gg = tid & 31, mg = tid >> 5;
    const u32x4* wt = (const u32x4*)w1T;
    float acc[8][4];
    #pragma unroll
    for (int i = 0; i < 8; ++i)
        #pragma unroll
        for (int r = 0; r < 4; ++r) acc[i][r] = 0.0f;
    for (int k8 = 0; k8 < 32; ++k8) {
        u32x4 w[8], h[4];
        #pragma unroll
        for (int i = 0; i < 8; ++i) w[i] = wt[(size_t)k8 * 256 + gg + 32 * i];
        #pragma unroll
        for (int r = 0; r < 4; ++r) h[r] = hs[mg * 4 + r][k8];
        #pragma unroll
        for (int i = 0; i < 8; ++i)
            #pragma unroll
            for (int r = 0; r < 4; ++r)
                acc[i][r] = dot_u4(w[i], h[r], acc[i][r]);
    }
    float pv[4] = {0, 0, 0, 0};
    #pragma unroll
    for (int i = 0; i < 8; ++i) {
        int g = gg + 32 * i;
        float bias = b1[g], w2g = w2[g];
        #pragma unroll
        for (int r = 0; r < 4; ++r)
            pv[r] += w2g * fmaxf(acc[i][r] + bias, 0.0f);
    }
    #pragma unroll
    for (int r = 0; r < 4; ++r) {
        pv[r] += __shfl_xor(pv[r], 1, 64);
        pv[r] += __shfl_xor(pv[r], 2, 64);
        pv[r] += __shfl_xor(pv[r], 4, 64);
        pv[r] += __shfl_xor(pv[r], 8, 64);
        pv[r] += __shfl_xor(pv[r], 16, 64);
    }
    if (gg == 0) {
        #pragma unroll
        for (int r = 0; r < 4; ++r) red[mg][r] = pv[r];
    }
    __syncthreads();
    if (tid < 64) {
        int m = m0 + tid;
        float v = fmaxf(red[tid >> 2][tid & 3] + b2[0], 0.0f);
        int b = m >> lgC, tl = m & (C - 1);
        out[(size_t)b * T_ + t0 + tl] = v;
    }
}

// ---------- GRU recurrence: 12 planes VGPR + 16 planes LDS + 20 streamed ----------
// tid = 2j+hf. Per-thread weight slice = 48 u32x4:
//   r u=0..3 streamed, r u=4..15 VGPR-resident, z u=0..15 streamed, n u=0..15 LDS.
// LDS n-slabs are THREAD-MAJOR (slab[s][tid]) -> each thread reads its own slot:
// consecutive-lane pattern, conflict-free. hq halves at 17-u32x4 stride ->
// adjacent bank groups, conflict-free broadcast.
__device__ __forceinline__ void rec_body(const uint32_t* __restrict__ whh,
        const float* __restrict__ bhh, const float* __restrict__ xg,
        f16* __restrict__ hout, float* __restrict__ state,
        int b, int C, char* smem) {
    int tid = threadIdx.x;
    int j = tid >> 1, hf = tid & 1;
    const u32x4* wb = (const u32x4*)whh;
    u32x4* wlds = (u32x4*)smem;                             // [16][512]
    u32x4 (*hq)[2][17] = (u32x4(*)[2][17])(smem + 131072);  // [2][2][17]

    // stage n-gate planes, thread-major (each thread writes/reads its own slot)
    #pragma unroll
    for (int s = 0; s < 16; ++s)
        wlds[s * 512 + tid] = wb[(32 + s) * 512 + tid];

    // resident r-planes u=4..15 (12 u32x4 = 48 VGPRs)
    u32x4 R4  = wb[ 4 * 512 + tid], R5  = wb[ 5 * 512 + tid];
    u32x4 R6  = wb[ 6 * 512 + tid], R7  = wb[ 7 * 512 + tid];
    u32x4 R8  = wb[ 8 * 512 + tid], R9  = wb[ 9 * 512 + tid];
    u32x4 R10 = wb[10 * 512 + tid], R11 = wb[11 * 512 + tid];
    u32x4 R12 = wb[12 * 512 + tid], R13 = wb[13 * 512 + tid];
    u32x4 R14 = wb[14 * 512 + tid], R15 = wb[15 * 512 + tid];

    float h_old = 0.0f, bhr = 0.0f, bhz = 0.0f, bhn = 0.0f;
    if (hf == 0) {
        h_old = state[b * 256 + j];
        bhr = bhh[j]; bhz = bhh[256 + j]; bhn = bhh[512 + j];
        ((f16*)&hq[0][j >> 7][0])[j & 127] = (f16)h_old;
    }
    __syncthreads();

    const float* xgt = xg + (size_t)b * C * G_;
    f16* hob = hout + (size_t)b * C * H_;
    const u32x4* nl = wlds + tid;

    for (int tl = 0; tl < C; ++tl) {
        int p = tl & 1;
        float xr = 0, xz = 0, xn = 0;
        if (hf == 0) { xr = xgt[j]; xz = xgt[256 + j]; xn = xgt[512 + j]; }

        // streamed r u=0..3
        u32x4 S0 = wb[0 * 512 + tid], S1 = wb[1 * 512 + tid];
        u32x4 S2 = wb[2 * 512 + tid], S3 = wb[3 * 512 + tid];

        const u32x4* hp = &hq[p][hf][0];
        float aR = 0.0f, aZ = 0.0f, aN = 0.0f;

#define STEPU(u, WR) { u32x4 hv = hp[u]; \
        u32x4 wz = wb[(16 + (u)) * 512 + tid]; \
        u32x4 wn = nl[(u) * 512]; \
        aR = dot_u4(WR, hv, aR); \
        aZ = dot_u4(wz, hv, aZ); \
        aN = dot_u4(wn, hv, aN); }

        STEPU(0, S0)  STEPU(1, S1)  STEPU(2, S2)  STEPU(3, S3)
        STEPU(4, R4)  STEPU(5, R5)  STEPU(6, R6)  STEPU(7, R7)
        STEPU(8, R8)  STEPU(9, R9)  STEPU(10, R10) STEPU(11, R11)
        STEPU(12, R12) STEPU(13, R13) STEPU(14, R14) STEPU(15, R15)
#undef STEPU

        // combine the two K-halves (adjacent lanes 2j / 2j+1)
        aR += __shfl_xor(aR, 1, 64);
        aZ += __shfl_xor(aZ, 1, 64);
        aN += __shfl_xor(aN, 1, 64);

        if (hf == 0) {
            float r = sigmoid_f(xr + aR + bhr);
            float z = sigmoid_f(xz + aZ + bhz);
            float n = tanh_f(xn + r * (aN + bhn));
            h_old = z * (h_old - n) + n;   // (1-z)*n + z*h
            f16 hh = (f16)h_old;
            hob[(size_t)tl * H_ + j] = hh;
            ((f16*)&hq[p ^ 1][j >> 7][0])[j & 127] = hh;
        }
        __syncthreads();
        xgt += G_;
    }
    if (hf == 0) state[b * 256 + j] = h_old;
}

// =======================================================================
// fused dispatch, depth-3 pipeline:
//   [0,64)        rec0(i)      xg0[i&1]   -> h1[i&1]
//   [64,128)      rec1(i-2)    xg1[(i-2)&1] -> h2[(i-2)&1]
//   [128,128+C)   xg0(i+1)     -> xg0[(i+1)&1]
//   [128+C,128+4C) xg1(i-1)    h1[(i-1)&1] -> xg1[(i-1)&1]
//   [128+4C,128+5C) reg(i-3)   h2[(i-3)&1] -> out
// =======================================================================
__global__ __launch_bounds__(512) void fused_step(int i, int nC, int C, int lgC,
        const float* __restrict__ x,
        const float* __restrict__ wih0, const float* __restrict__ bih0,
        const uint32_t* __restrict__ whh0, const float* __restrict__ bhh0,
        const uint32_t* __restrict__ whh1, const float* __restrict__ bhh1,
        const uint32_t* __restrict__ wih1T, const float* __restrict__ bih1,
        const uint32_t* __restrict__ w1T, const float* __restrict__ b1,
        const float* __restrict__ w2, const float* __restrict__ b2,
        float* __restrict__ xg0a, float* __restrict__ xg0b,
        float* __restrict__ xg1a, float* __restrict__ xg1b,
        f16* __restrict__ h1a, f16* __restrict__ h1b,
        f16* __restrict__ h2a, f16* __restrict__ h2b,
        float* __restrict__ st0, float* __restrict__ st1,
        float* __restrict__ out) {
    extern __shared__ __align__(16) char smem[];
    int blk = blockIdx.x;
    if (blk < 64) {
        if (i >= nC) return;
        rec_body(whh0, bhh0, (i & 1) ? xg0b : xg0a,
                 (i & 1) ? h1b : h1a, st0, blk, C, smem);
    } else if (blk < 128) {
        int c = i - 2;
        if (c < 0 || c >= nC) return;
        rec_body(whh1, bhh1, (c & 1) ? xg1b : xg1a,
                 (c & 1) ? h2b : h2a, st1, blk - 64, C, smem);
    } else if (blk < 128 + C) {
        int c = i + 1;
        if (c >= nC) return;
        xg0_body(x, wih0, bih0, (c & 1) ? xg0b : xg0a, c * C, C, blk - 128, smem);
    } else if (blk < 128 + 4 * C) {
        int c = i - 1;
        if (c < 0 || c >= nC) return;
        xg1_body((c & 1) ? h1b : h1a, wih1T, bih1,
                 (c & 1) ? xg1b : xg1a, C, lgC, blk - 128 - C, smem);
    } else {
        int c = i - 3;
        if (c < 0 || c >= nC) return;
        reg_body((c & 1) ? h2b : h2a, w1T, b1, w2, b2, out, c * C, C, lgC,
                 blk - 128 - 4 * C, smem);
    }
}

// ---------- standalone xg0 (chunk 0 prelaunch) ----------
__global__ __launch_bounds__(512) void xg0_stand(const float* __restrict__ x,
        const float* __restrict__ wih0, const float* __restrict__ bih0,
        float* __restrict__ xg, int t0, int C) {
    __shared__ __align__(16) char smem[4096];
    xg0_body(x, wih0, bih0, xg, t0, C, blockIdx.x, smem);
}

// ---------- host ----------
extern "C" void kernel_launch(void* const* d_in, const int* in_sizes, int n_in,
                              void* d_out, int out_size, void* d_ws, size_t ws_size,
                              hipStream_t stream) {
    const float* x    = (const float*)d_in[0];
    const float* Wih0 = (const float*)d_in[1];
    const float* Whh0 = (const float*)d_in[2];
    const float* bih0 = (const float*)d_in[3];
    const float* bhh0 = (const float*)d_in[4];
    const float* Wih1 = (const float*)d_in[5];
    const float* Whh1 = (const float*)d_in[6];
    const float* bih1 = (const float*)d_in[7];
    const float* bhh1 = (const float*)d_in[8];
    const float* W1   = (const float*)d_in[9];
    const float* b1   = (const float*)d_in[10];
    const float* W2   = (const float*)d_in[11];
    const float* b2   = (const float*)d_in[12];
    float* out = (float*)d_out;

    hipFuncSetAttribute(reinterpret_cast<const void*>(fused_step),
                        hipFuncAttributeMaxDynamicSharedMemorySize, REC_SMEM);

    char* ws = (char*)d_ws;
    uint32_t* wcvt = (uint32_t*)ws;             // 327680 dwords
    const uint32_t* whh0c = wcvt;
    const uint32_t* whh1c = wcvt + 98304;
    const uint32_t* wih1T = wcvt + 196608;
    const uint32_t* w1T   = wcvt + 294912;
    float* state0 = (float*)(ws + 1310720);
    float* state1 = (float*)(ws + 1310720 + 65536);
    size_t fixed = 1310720 + 2 * 65536;

    // per-chunk: xg0 x2 + xg1 x2 (196608C each) + h1 x2 + h2 x2 (32768C each)
    int C = 512;
    while (C > 32 && fixed + (size_t)C * 917504 > ws_size) C >>= 1;
    int lgC = 0; while ((1 << lgC) < C) lgC++;
    int nC = T_ / C;

    char* p = ws + fixed;
    float* xg0_buf[2]; float* xg1_buf[2];
    f16* h1_buf[2]; f16* h2_buf[2];
    xg0_buf[0] = (float*)p;  p += (size_t)C * 196608;
    xg0_buf[1] = (float*)p;  p += (size_t)C * 196608;
    xg1_buf[0] = (float*)p;  p += (size_t)C * 196608;
    xg1_buf[1] = (float*)p;  p += (size_t)C * 196608;
    h1_buf[0] = (f16*)p;     p += (size_t)C * 32768;
    h1_buf[1] = (f16*)p;     p += (size_t)C * 32768;
    h2_buf[0] = (f16*)p;     p += (size_t)C * 32768;
    h2_buf[1] = (f16*)p;

    cvt_weights<<<1280, 256, 0, stream>>>(Whh0, Whh1, Wih1, W1, wcvt);
    hipMemsetAsync(state0, 0, 2 * 65536, stream);
    xg0_stand<<<C, 512, 0, stream>>>(x, Wih0, bih0, xg0_buf[0], 0, C);

    for (int i = 0; i <= nC + 2; ++i) {
        fused_step<<<128 + 5 * C, 512, REC_SMEM, stream>>>(i, nC, C, lgC,
            x, Wih0, bih0, whh0c, bhh0, whh1c, bhh1, wih1T, bih1, w1T, b1, W2, b2,
            xg0_buf[0], xg0_buf[1], xg1_buf[0], xg1_buf[1],
            h1_buf[0], h1_buf[1], h2_buf[0], h2_buf[1],
            state0, state1, out);
    }
}

// Round 11
// 2822.906 us; speedup vs baseline: 2.2503x; 1.0705x over previous
//
#include <hip/hip_runtime.h>
#include <hip/hip_fp16.h>
#include <stdint.h>

#define B_ 64
#define T_ 2048
#define I_ 16
#define H_ 256
#define G_ 768   // 3*H

// dynamic LDS: 17 weight slabs thread-major (139264) + hq[2][2][17] u32x4 (1088)
#define REC_SMEM 140352

typedef _Float16 f16;
typedef _Float16 half2_t __attribute__((ext_vector_type(2)));
typedef uint32_t u32x4 __attribute__((ext_vector_type(4)));

// ---------- fast math helpers ----------
__device__ __forceinline__ float fast_rcp(float x) {
#if __has_builtin(__builtin_amdgcn_rcpf)
    return __builtin_amdgcn_rcpf(x);
#else
    return 1.0f / x;
#endif
}
__device__ __forceinline__ float sigmoid_f(float x) {
    return fast_rcp(1.0f + __expf(-x));
}
__device__ __forceinline__ float tanh_f(float x) {
    float e = __expf(2.0f * x);
    return 1.0f - 2.0f * fast_rcp(e + 1.0f);
}

__device__ __forceinline__ float fdot2(uint32_t a, uint32_t b, float c) {
#if __has_builtin(__builtin_amdgcn_fdot2)
    return __builtin_amdgcn_fdot2(__builtin_bit_cast(half2_t, a),
                                  __builtin_bit_cast(half2_t, b), c, false);
#else
    half2_t ha = __builtin_bit_cast(half2_t, a), hb = __builtin_bit_cast(half2_t, b);
    return c + (float)ha.x * (float)hb.x + (float)ha.y * (float)hb.y;
#endif
}
__device__ __forceinline__ float dot_u4(u32x4 w, u32x4 h, float acc) {
    acc = fdot2(w.x, h.x, acc);
    acc = fdot2(w.y, h.y, acc);
    acc = fdot2(w.z, h.z, acc);
    acc = fdot2(w.w, h.w, acc);
    return acc;
}

// ---------- weight fp32 -> packed fp16 conversion ----------
// Whh layers (dwords [0,98304) L0, [98304,196608) L1): 48 thread-major planes.
//   u32x4 index within layer: P*512 + tid, P = gate*16+u (r=0,z=1,n=2),
//   tid = 2j+hf -> row = gate*256+j, halves hf*128+u*8 .. +8.
// [196608,294912) Wih1T k-major: u32x4 = k8*768 + g
// [294912,327680) W1T   k-major: u32x4 = k8*256 + g
__global__ __launch_bounds__(256) void cvt_weights(const float* __restrict__ whh0,
                                                   const float* __restrict__ whh1,
                                                   const float* __restrict__ wih1,
                                                   const float* __restrict__ w1,
                                                   uint32_t* __restrict__ out) {
    int idx = blockIdx.x * 256 + threadIdx.x;
    if (idx >= 327680) return;
    const float* s;
    if (idx < 196608) {
        const float* w = (idx < 98304) ? whh0 : whh1;
        int lidx = (idx < 98304) ? idx : idx - 98304;
        int u4 = lidx >> 2, d = lidx & 3;
        int P = u4 >> 9, t = u4 & 511;
        int j = t >> 1, hf = t & 1;
        int gate = P >> 4, u = P & 15;
        int row = gate * 256 + j;
        int halfoff = hf * 128 + u * 8;
        s = w + (size_t)row * 256 + halfoff + d * 2;
    } else if (idx < 294912) {
        int local = idx - 196608;
        int u4 = local >> 2, d = local & 3;
        int k8 = u4 / 768, g = u4 - k8 * 768;
        s = wih1 + (size_t)g * 256 + k8 * 8 + d * 2;
    } else {
        int local = idx - 294912;
        int u4 = local >> 2, d = local & 3;
        int k8 = u4 >> 8, g = u4 & 255;
        s = w1 + (size_t)g * 256 + k8 * 8 + d * 2;
    }
    half2_t h;
    h.x = (f16)s[0];
    h.y = (f16)s[1];
    out[idx] = __builtin_bit_cast(uint32_t, h);
}

// =======================================================================
// role bodies (512 threads each)
// =======================================================================

// ---------- xg0 = bih0 + x @ Wih0^T (K=16, fp32), one 64-row tile ----------
__device__ __forceinline__ void xg0_body(const float* __restrict__ x,
        const float* __restrict__ wih0, const float* __restrict__ bih0,
        float* __restrict__ xg, int t0, int C, int blk, char* smem) {
    float (*xs)[16] = (float(*)[16])smem;
    int tid = threadIdx.x;
    int m0 = blk * 64;
    if (tid < 256) {
        int r = tid >> 2, c4 = (tid & 3) * 4;
        int m = m0 + r;
        int b = m / C, tl = m - b * C;
        float4 v = *(const float4*)(x + (size_t)(b * T_ + t0 + tl) * I_ + c4);
        *(float4*)&xs[r][c4] = v;
    }
    __syncthreads();
    for (int g = tid; g < G_; g += 512) {
        const float4* wr = (const float4*)(wih0 + (size_t)g * I_);
        float4 w0 = wr[0], w1 = wr[1], w2 = wr[2], w3 = wr[3];
        float bias = bih0[g];
        float* outp = xg + (size_t)m0 * G_ + g;
        for (int m = 0; m < 64; ++m) {
            const float4* xr4 = (const float4*)xs[m];
            float4 a0 = xr4[0], a1 = xr4[1], a2 = xr4[2], a3 = xr4[3];
            float acc = bias;
            acc += a0.x*w0.x + a0.y*w0.y + a0.z*w0.z + a0.w*w0.w;
            acc += a1.x*w1.x + a1.y*w1.y + a1.z*w1.z + a1.w*w1.w;
            acc += a2.x*w2.x + a2.y*w2.y + a2.z*w2.z + a2.w*w2.w;
            acc += a3.x*w3.x + a3.y*w3.y + a3.z*w3.z + a3.w*w3.w;
            outp[(size_t)m * G_] = acc;
        }
    }
}

// ---------- xg1 = bih1 + h1 @ Wih1^T, 8g x 4m tile; blk in [0,3C) ----------
__device__ __forceinline__ void xg1_body(const f16* __restrict__ h1,
        const uint32_t* __restrict__ wih1T, const float* __restrict__ bih1,
        float* __restrict__ xg, int C, int lgC, int blk, char* smem) {
    u32x4 (*hs)[32] = (u32x4(*)[32])smem;   // 32 KB
    int tid = threadIdx.x;
    int m0 = (blk & (C - 1)) * 64;
    int gbase = (blk >> lgC) * 256;
    const u32x4* hsrc = (const u32x4*)h1 + (size_t)m0 * 32;
    #pragma unroll
    for (int it = 0; it < 4; ++it) {
        int o = tid + it * 512;
        hs[o >> 5][o & 31] = hsrc[o];
    }
    __syncthreads();
    int gg = tid & 31, mg = tid >> 5;       // mg in [0,16)
    const u32x4* wt = (const u32x4*)wih1T;
    float acc[8][4];
    #pragma unroll
    for (int i = 0; i < 8; ++i)
        #pragma unroll
        for (int r = 0; r < 4; ++r) acc[i][r] = 0.0f;
    for (int k8 = 0; k8 < 32; ++k8) {
        u32x4 w[8], h[4];
        #pragma unroll
        for (int i = 0; i < 8; ++i) w[i] = wt[(size_t)k8 * 768 + gbase + gg + 32 * i];
        #pragma unroll
        for (int r = 0; r < 4; ++r) h[r] = hs[mg * 4 + r][k8];
        #pragma unroll
        for (int i = 0; i < 8; ++i)
            #pragma unroll
            for (int r = 0; r < 4; ++r)
                acc[i][r] = dot_u4(w[i], h[r], acc[i][r]);
    }
    #pragma unroll
    for (int i = 0; i < 8; ++i) {
        int g = gbase + gg + 32 * i;
        float bias = bih1[g];
        #pragma unroll
        for (int r = 0; r < 4; ++r)
            xg[(size_t)(m0 + mg * 4 + r) * G_ + g] = acc[i][r] + bias;
    }
}

// ---------- regressor, 8g x 4m tile ----------
__device__ __forceinline__ void reg_body(const f16* __restrict__ h2,
        const uint32_t* __restrict__ w1T, const float* __restrict__ b1,
        const float* __restrict__ w2, const float* __restrict__ b2,
        float* __restrict__ out, int t0, int C, int lgC, int blk, char* smem) {
    u32x4 (*hs)[32] = (u32x4(*)[32])smem;            // 32 KB
    float (*red)[4] = (float(*)[4])(smem + 32768);   // [16][4]
    int tid = threadIdx.x;
    int m0 = blk * 64;
    const u32x4* hsrc = (const u32x4*)h2 + (size_t)m0 * 32;
    #pragma unroll
    for (int it = 0; it < 4; ++it) {
        int o = tid + it * 512;
        hs[o >> 5][o & 31] = hsrc[o];
    }
    __syncthreads();
    int gg = tid & 31, mg = tid >> 5;
    const u32x4* wt = (const u32x4*)w1T;
    float acc[8][4];
    #pragma unroll
    for (int i = 0; i < 8; ++i)
        #pragma unroll
        for (int r = 0; r < 4; ++r) acc[i][r] = 0.0f;
    for (int k8 = 0; k8 < 32; ++k8) {
        u32x4 w[8], h[4];
        #pragma unroll
        for (int i = 0; i < 8; ++i) w[i] = wt[(size_t)k8 * 256 + gg + 32 * i];
        #pragma unroll
        for (int r = 0; r < 4; ++r) h[r] = hs[mg * 4 + r][k8];
        #pragma unroll
        for (int i = 0; i < 8; ++i)
            #pragma unroll
            for (int r = 0; r < 4; ++r)
                acc[i][r] = dot_u4(w[i], h[r], acc[i][r]);
    }
    float pv[4] = {0, 0, 0, 0};
    #pragma unroll
    for (int i = 0; i < 8; ++i) {
        int g = gg + 32 * i;
        float bias = b1[g], w2g = w2[g];
        #pragma unroll
        for (int r = 0; r < 4; ++r)
            pv[r] += w2g * fmaxf(acc[i][r] + bias, 0.0f);
    }
    #pragma unroll
    for (int r = 0; r < 4; ++r) {
        pv[r] += __shfl_xor(pv[r], 1, 64);
        pv[r] += __shfl_xor(pv[r], 2, 64);
        pv[r] += __shfl_xor(pv[r], 4, 64);
        pv[r] += __shfl_xor(pv[r], 8, 64);
        pv[r] += __shfl_xor(pv[r], 16, 64);
    }
    if (gg == 0) {
        #pragma unroll
        for (int r = 0; r < 4; ++r) red[mg][r] = pv[r];
    }
    __syncthreads();
    if (tid < 64) {
        int m = m0 + tid;
        float v = fmaxf(red[tid >> 2][tid & 3] + b2[0], 0.0f);
        int b = m >> lgC, tl = m & (C - 1);
        out[(size_t)b * T_ + t0 + tl] = v;
    }
}

// ---------- GRU recurrence: 18 planes VGPR + 17 planes LDS + 13 streamed ----------
// tid = 2j+hf. Planes (P = gate*16+u): resident r u=0..15 (P0-15), z u=0..1
// (P16-17); LDS n u=0..15 (P32-47, slabs 0-15) + z u=2 (P18, slab 16);
// streamed z u=3..15 (P19-31), issued with ~6-plane lookahead.
__device__ __forceinline__ void rec_body(const uint32_t* __restrict__ whh,
        const float* __restrict__ bhh, const float* __restrict__ xg,
        f16* __restrict__ hout, float* __restrict__ state,
        int b, int C, char* smem) {
    int tid = threadIdx.x;
    int j = tid >> 1, hf = tid & 1;
    const u32x4* wb = (const u32x4*)whh;
    u32x4* wlds = (u32x4*)smem;                              // 17 slabs x [512]
    u32x4 (*hq)[2][17] = (u32x4(*)[2][17])(smem + 139264);

    // stage slabs thread-major (each thread owns its slot; conflict-free)
    #pragma unroll
    for (int s = 0; s < 16; ++s)
        wlds[s * 512 + tid] = wb[(32 + s) * 512 + tid];
    wlds[16 * 512 + tid] = wb[18 * 512 + tid];

    // resident planes
    u32x4 R0  = wb[ 0 * 512 + tid], R1  = wb[ 1 * 512 + tid];
    u32x4 R2  = wb[ 2 * 512 + tid], R3  = wb[ 3 * 512 + tid];
    u32x4 R4  = wb[ 4 * 512 + tid], R5  = wb[ 5 * 512 + tid];
    u32x4 R6  = wb[ 6 * 512 + tid], R7  = wb[ 7 * 512 + tid];
    u32x4 R8  = wb[ 8 * 512 + tid], R9  = wb[ 9 * 512 + tid];
    u32x4 R10 = wb[10 * 512 + tid], R11 = wb[11 * 512 + tid];
    u32x4 R12 = wb[12 * 512 + tid], R13 = wb[13 * 512 + tid];
    u32x4 R14 = wb[14 * 512 + tid], R15 = wb[15 * 512 + tid];
    u32x4 Z0  = wb[16 * 512 + tid], Z1  = wb[17 * 512 + tid];

    float h_old = 0.0f, bhr = 0.0f, bhz = 0.0f, bhn = 0.0f;
    if (hf == 0) {
        h_old = state[b * 256 + j];
        bhr = bhh[j]; bhz = bhh[256 + j]; bhn = bhh[512 + j];
        ((f16*)&hq[0][j >> 7][0])[j & 127] = (f16)h_old;
    }
    __syncthreads();

    const float* xgt = xg + (size_t)b * C * G_;
    f16* hob = hout + (size_t)b * C * H_;
    const u32x4* nl = wlds + tid;

    for (int tl = 0; tl < C; ++tl) {
        int p = tl & 1;
        float xr = 0, xz = 0, xn = 0;
        if (hf == 0) { xr = xgt[j]; xz = xgt[256 + j]; xn = xgt[512 + j]; }

        const u32x4* hp = &hq[p][hf][0];
        float aR = 0.0f, aZ = 0.0f, aN = 0.0f;

#define PU(u, ZSRC) { u32x4 hv = hp[u]; \
        aR = dot_u4(R##u, hv, aR); \
        aN = dot_u4(nl[(u) * 512], hv, aN); \
        aZ = dot_u4(ZSRC, hv, aZ); }

        // stream window: issue 6 ahead, consume in order
        u32x4 S3 = wb[19 * 512 + tid], S4 = wb[20 * 512 + tid];
        u32x4 S5 = wb[21 * 512 + tid], S6 = wb[22 * 512 + tid];
        u32x4 S7 = wb[23 * 512 + tid], S8 = wb[24 * 512 + tid];

        PU(0, Z0)
        PU(1, Z1)
        PU(2, nl[16 * 512])
        PU(3, S3)  u32x4 S9  = wb[25 * 512 + tid];
        PU(4, S4)  u32x4 S10 = wb[26 * 512 + tid];
        PU(5, S5)  u32x4 S11 = wb[27 * 512 + tid];
        PU(6, S6)  u32x4 S12 = wb[28 * 512 + tid];
        PU(7, S7)  u32x4 S13 = wb[29 * 512 + tid];
        PU(8, S8)  u32x4 S14 = wb[30 * 512 + tid];
        PU(9, S9)  u32x4 S15 = wb[31 * 512 + tid];
        PU(10, S10)
        PU(11, S11)
        PU(12, S12)
        PU(13, S13)
        PU(14, S14)
        PU(15, S15)
#undef PU

        // combine the two K-halves (adjacent lanes 2j / 2j+1)
        aR += __shfl_xor(aR, 1, 64);
        aZ += __shfl_xor(aZ, 1, 64);
        aN += __shfl_xor(aN, 1, 64);

        if (hf == 0) {
            float r = sigmoid_f(xr + aR + bhr);
            float z = sigmoid_f(xz + aZ + bhz);
            float n = tanh_f(xn + r * (aN + bhn));
            h_old = z * (h_old - n) + n;   // (1-z)*n + z*h
            f16 hh = (f16)h_old;
            hob[(size_t)tl * H_ + j] = hh;
            ((f16*)&hq[p ^ 1][j >> 7][0])[j & 127] = hh;
        }
        __syncthreads();
        xgt += G_;
    }
    if (hf == 0) state[b * 256 + j] = h_old;
}

// =======================================================================
// fused dispatch, depth-3 pipeline:
//   [0,64)          rec0(i)
//   [64,128)        rec1(i-2)
//   [128,128+C)     xg0(i+1)
//   [128+C,128+4C)  xg1(i-1)
//   [128+4C,128+5C) reg(i-3)
// =======================================================================
__global__ __launch_bounds__(512)
__attribute__((amdgpu_waves_per_eu(2, 2)))
void fused_step(int i, int nC, int C, int lgC,
        const float* __restrict__ x,
        const float* __restrict__ wih0, const float* __restrict__ bih0,
        const uint32_t* __restrict__ whh0, const float* __restrict__ bhh0,
        const uint32_t* __restrict__ whh1, const float* __restrict__ bhh1,
        const uint32_t* __restrict__ wih1T, const float* __restrict__ bih1,
        const uint32_t* __restrict__ w1T, const float* __restrict__ b1,
        const float* __restrict__ w2, const float* __restrict__ b2,
        float* __restrict__ xg0a, float* __restrict__ xg0b,
        float* __restrict__ xg1a, float* __restrict__ xg1b,
        f16* __restrict__ h1a, f16* __restrict__ h1b,
        f16* __restrict__ h2a, f16* __restrict__ h2b,
        float* __restrict__ st0, float* __restrict__ st1,
        float* __restrict__ out) {
    extern __shared__ __align__(16) char smem[];
    int blk = blockIdx.x;
    if (blk < 64) {
        if (i >= nC) return;
        rec_body(whh0, bhh0, (i & 1) ? xg0b : xg0a,
                 (i & 1) ? h1b : h1a, st0, blk, C, smem);
    } else if (blk < 128) {
        int c = i - 2;
        if (c < 0 || c >= nC) return;
        rec_body(whh1, bhh1, (c & 1) ? xg1b : xg1a,
                 (c & 1) ? h2b : h2a, st1, blk - 64, C, smem);
    } else if (blk < 128 + C) {
        int c = i + 1;
        if (c >= nC) return;
        xg0_body(x, wih0, bih0, (c & 1) ? xg0b : xg0a, c * C, C, blk - 128, smem);
    } else if (blk < 128 + 4 * C) {
        int c = i - 1;
        if (c < 0 || c >= nC) return;
        xg1_body((c & 1) ? h1b : h1a, wih1T, bih1,
                 (c & 1) ? xg1b : xg1a, C, lgC, blk - 128 - C, smem);
    } else {
        int c = i - 3;
        if (c < 0 || c >= nC) return;
        reg_body((c & 1) ? h2b : h2a, w1T, b1, w2, b2, out, c * C, C, lgC,
                 blk - 128 - 4 * C, smem);
    }
}

// ---------- standalone xg0 (chunk 0 prelaunch) ----------
__global__ __launch_bounds__(512) void xg0_stand(const float* __restrict__ x,
        const float* __restrict__ wih0, const float* __restrict__ bih0,
        float* __restrict__ xg, int t0, int C) {
    __shared__ __align__(16) char smem[4096];
    xg0_body(x, wih0, bih0, xg, t0, C, blockIdx.x, smem);
}

// ---------- host ----------
extern "C" void kernel_launch(void* const* d_in, const int* in_sizes, int n_in,
                              void* d_out, int out_size, void* d_ws, size_t ws_size,
                              hipStream_t stream) {
    const float* x    = (const float*)d_in[0];
    const float* Wih0 = (const float*)d_in[1];
    const float* Whh0 = (const float*)d_in[2];
    const float* bih0 = (const float*)d_in[3];
    const float* bhh0 = (const float*)d_in[4];
    const float* Wih1 = (const float*)d_in[5];
    const float* Whh1 = (const float*)d_in[6];
    const float* bih1 = (const float*)d_in[7];
    const float* bhh1 = (const float*)d_in[8];
    const float* W1   = (const float*)d_in[9];
    const float* b1   = (const float*)d_in[10];
    const float* W2   = (const float*)d_in[11];
    const float* b2   = (const float*)d_in[12];
    float* out = (float*)d_out;

    hipFuncSetAttribute(reinterpret_cast<const void*>(fused_step),
                        hipFuncAttributeMaxDynamicSharedMemorySize, REC_SMEM);

    char* ws = (char*)d_ws;
    uint32_t* wcvt = (uint32_t*)ws;             // 327680 dwords
    const uint32_t* whh0c = wcvt;
    const uint32_t* whh1c = wcvt + 98304;
    const uint32_t* wih1T = wcvt + 196608;
    const uint32_t* w1T   = wcvt + 294912;
    float* state0 = (float*)(ws + 1310720);
    float* state1 = (float*)(ws + 1310720 + 65536);
    size_t fixed = 1310720 + 2 * 65536;

    // per-chunk: xg0 x2 + xg1 x2 (196608C each) + h1 x2 + h2 x2 (32768C each)
    // C=128: smaller chunks cut the depth-3 pipeline fill/drain overhead.
    int C = 128;
    while (C > 32 && fixed + (size_t)C * 917504 > ws_size) C >>= 1;
    int lgC = 0; while ((1 << lgC) < C) lgC++;
    int nC = T_ / C;

    char* p = ws + fixed;
    float* xg0_buf[2]; float* xg1_buf[2];
    f16* h1_buf[2]; f16* h2_buf[2];
    xg0_buf[0] = (float*)p;  p += (size_t)C * 196608;
    xg0_buf[1] = (float*)p;  p += (size_t)C * 196608;
    xg1_buf[0] = (float*)p;  p += (size_t)C * 196608;
    xg1_buf[1] = (float*)p;  p += (size_t)C * 196608;
    h1_buf[0] = (f16*)p;     p += (size_t)C * 32768;
    h1_buf[1] = (f16*)p;     p += (size_t)C * 32768;
    h2_buf[0] = (f16*)p;     p += (size_t)C * 32768;
    h2_buf[1] = (f16*)p;

    cvt_weights<<<1280, 256, 0, stream>>>(Whh0, Whh1, Wih1, W1, wcvt);
    hipMemsetAsync(state0, 0, 2 * 65536, stream);
    xg0_stand<<<C, 512, 0, stream>>>(x, Wih0, bih0, xg0_buf[0], 0, C);

    for (int i = 0; i <= nC + 2; ++i) {
        fused_step<<<128 + 5 * C, 512, REC_SMEM, stream>>>(i, nC, C, lgC,
            x, Wih0, bih0, whh0c, bhh0, whh1c, bhh1, wih1T, bih1, w1T, b1, W2, b2,
            xg0_buf[0], xg0_buf[1], xg1_buf[0], xg1_buf[1],
            h1_buf[0], h1_buf[1], h2_buf[0], h2_buf[1],
            state0, state1, out);
    }
}

// Round 12
// 2788.209 us; speedup vs baseline: 2.2783x; 1.0124x over previous
//
#include <hip/hip_runtime.h>
#include <hip/hip_fp16.h>
#include <stdint.h>

#define B_ 64
#define T_ 2048
#define I_ 16
#define H_ 256
#define G_ 768   // 3*H

// dynamic LDS: 19 weight slabs thread-major (155648) + hq[2][2][17] u32x4 (1088)
#define REC_SMEM 156736

typedef _Float16 f16;
typedef _Float16 half2_t __attribute__((ext_vector_type(2)));
typedef uint32_t u32x4 __attribute__((ext_vector_type(4)));
typedef uint32_t u32x2 __attribute__((ext_vector_type(2)));

// ---------- fast math helpers ----------
__device__ __forceinline__ float fast_rcp(float x) {
#if __has_builtin(__builtin_amdgcn_rcpf)
    return __builtin_amdgcn_rcpf(x);
#else
    return 1.0f / x;
#endif
}
__device__ __forceinline__ float sigmoid_f(float x) {
    return fast_rcp(1.0f + __expf(-x));
}
__device__ __forceinline__ float tanh_f(float x) {
    float e = __expf(2.0f * x);
    return 1.0f - 2.0f * fast_rcp(e + 1.0f);
}

__device__ __forceinline__ float fdot2(uint32_t a, uint32_t b, float c) {
#if __has_builtin(__builtin_amdgcn_fdot2)
    return __builtin_amdgcn_fdot2(__builtin_bit_cast(half2_t, a),
                                  __builtin_bit_cast(half2_t, b), c, false);
#else
    half2_t ha = __builtin_bit_cast(half2_t, a), hb = __builtin_bit_cast(half2_t, b);
    return c + (float)ha.x * (float)hb.x + (float)ha.y * (float)hb.y;
#endif
}
__device__ __forceinline__ float dot_u4(u32x4 w, u32x4 h, float acc) {
    acc = fdot2(w.x, h.x, acc);
    acc = fdot2(w.y, h.y, acc);
    acc = fdot2(w.z, h.z, acc);
    acc = fdot2(w.w, h.w, acc);
    return acc;
}

// ---------- weight conversion ----------
// Per Whh layer (stride 81920 dwords; L0 at 0, L1 at 81920):
//   [0,65536) dwords: 32 fp16 planes thread-major. u32x4 idx = P*512 + tid,
//     tid=2j+hf. P<16: z gate (row 256+j), u=P.  P>=16: n gate (row 512+j), u=P-16.
//     Covers halves hf*128 + u*8 .. +8.
//   [65536,81920) dwords: 16 fp8-e5m2 r-gate planes. u32x2 idx = P8*512 + tid,
//     byte k of pair = e5m2(round-nearest) of half hf*128 + P8*8 + k (row j).
// [163840,262144) Wih1T k-major fp16: u32x4 = k8*768 + g
// [262144,294912) W1T   k-major fp16: u32x4 = k8*256 + g
__global__ __launch_bounds__(256) void cvt_weights(const float* __restrict__ whh0,
                                                   const float* __restrict__ whh1,
                                                   const float* __restrict__ wih1,
                                                   const float* __restrict__ w1,
                                                   uint32_t* __restrict__ out) {
    int idx = blockIdx.x * 256 + threadIdx.x;
    if (idx >= 294912) return;
    if (idx < 163840) {
        const float* w = (idx < 81920) ? whh0 : whh1;
        int l = (idx < 81920) ? idx : idx - 81920;
        if (l < 65536) {
            int u4 = l >> 2, d = l & 3;
            int P = u4 >> 9, t = u4 & 511;
            int j = t >> 1, hf = t & 1;
            int row = (P < 16) ? (256 + j) : (512 + j);
            int u = (P < 16) ? P : P - 16;
            const float* s = w + (size_t)row * 256 + hf * 128 + u * 8 + d * 2;
            half2_t h;
            h.x = (f16)s[0];
            h.y = (f16)s[1];
            out[idx] = __builtin_bit_cast(uint32_t, h);
        } else {
            int l2 = l - 65536;
            int P8 = l2 >> 10, wd = l2 & 1023;
            int t = wd >> 1, piece = wd & 1;
            int j = t >> 1, hf = t & 1;
            const float* s = w + (size_t)j * 256 + hf * 128 + P8 * 8 + piece * 4;
            uint32_t dw = 0;
            #pragma unroll
            for (int k = 0; k < 4; ++k) {
                f16 hh = (f16)s[k];
                uint16_t hb = __builtin_bit_cast(uint16_t, hh);
                uint16_t r8 = (uint16_t)((hb + 0x7F + ((hb >> 8) & 1)) >> 8); // RN to e5m2
                dw |= (uint32_t)(r8 & 0xFF) << (8 * k);
            }
            out[idx] = dw;
        }
    } else if (idx < 262144) {
        int local = idx - 163840;
        int u4 = local >> 2, d = local & 3;
        int k8 = u4 / 768, g = u4 - k8 * 768;
        const float* s = wih1 + (size_t)g * 256 + k8 * 8 + d * 2;
        half2_t h; h.x = (f16)s[0]; h.y = (f16)s[1];
        out[idx] = __builtin_bit_cast(uint32_t, h);
    } else {
        int local = idx - 262144;
        int u4 = local >> 2, d = local & 3;
        int k8 = u4 >> 8, g = u4 & 255;
        const float* s = w1 + (size_t)g * 256 + k8 * 8 + d * 2;
        half2_t h; h.x = (f16)s[0]; h.y = (f16)s[1];
        out[idx] = __builtin_bit_cast(uint32_t, h);
    }
}

// =======================================================================
// role bodies (512 threads each)
// =======================================================================

__device__ __forceinline__ void xg0_body(const float* __restrict__ x,
        const float* __restrict__ wih0, const float* __restrict__ bih0,
        float* __restrict__ xg, int t0, int C, int blk, char* smem) {
    float (*xs)[16] = (float(*)[16])smem;
    int tid = threadIdx.x;
    int m0 = blk * 64;
    if (tid < 256) {
        int r = tid >> 2, c4 = (tid & 3) * 4;
        int m = m0 + r;
        int b = m / C, tl = m - b * C;
        float4 v = *(const float4*)(x + (size_t)(b * T_ + t0 + tl) * I_ + c4);
        *(float4*)&xs[r][c4] = v;
    }
    __syncthreads();
    for (int g = tid; g < G_; g += 512) {
        const float4* wr = (const float4*)(wih0 + (size_t)g * I_);
        float4 w0 = wr[0], w1 = wr[1], w2 = wr[2], w3 = wr[3];
        float bias = bih0[g];
        float* outp = xg + (size_t)m0 * G_ + g;
        for (int m = 0; m < 64; ++m) {
            const float4* xr4 = (const float4*)xs[m];
            float4 a0 = xr4[0], a1 = xr4[1], a2 = xr4[2], a3 = xr4[3];
            float acc = bias;
            acc += a0.x*w0.x + a0.y*w0.y + a0.z*w0.z + a0.w*w0.w;
            acc += a1.x*w1.x + a1.y*w1.y + a1.z*w1.z + a1.w*w1.w;
            acc += a2.x*w2.x + a2.y*w2.y + a2.z*w2.z + a2.w*w2.w;
            acc += a3.x*w3.x + a3.y*w3.y + a3.z*w3.z + a3.w*w3.w;
            outp[(size_t)m * G_] = acc;
        }
    }
}

__device__ __forceinline__ void xg1_body(const f16* __restrict__ h1,
        const uint32_t* __restrict__ wih1T, const float* __restrict__ bih1,
        float* __restrict__ xg, int C, int lgC, int blk, char* smem) {
    u32x4 (*hs)[32] = (u32x4(*)[32])smem;   // 32 KB
    int tid = threadIdx.x;
    int m0 = (blk & (C - 1)) * 64;
    int gbase = (blk >> lgC) * 256;
    const u32x4* hsrc = (const u32x4*)h1 + (size_t)m0 * 32;
    #pragma unroll
    for (int it = 0; it < 4; ++it) {
        int o = tid + it * 512;
        hs[o >> 5][o & 31] = hsrc[o];
    }
    __syncthreads();
    int gg = tid & 31, mg = tid >> 5;
    const u32x4* wt = (const u32x4*)wih1T;
    float acc[8][4];
    #pragma unroll
    for (int i = 0; i < 8; ++i)
        #pragma unroll
        for (int r = 0; r < 4; ++r) acc[i][r] = 0.0f;
    for (int k8 = 0; k8 < 32; ++k8) {
        u32x4 w[8], h[4];
        #pragma unroll
        for (int i = 0; i < 8; ++i) w[i] = wt[(size_t)k8 * 768 + gbase + gg + 32 * i];
        #pragma unroll
        for (int r = 0; r < 4; ++r) h[r] = hs[mg * 4 + r][k8];
        #pragma unroll
        for (int i = 0; i < 8; ++i)
            #pragma unroll
            for (int r = 0; r < 4; ++r)
                acc[i][r] = dot_u4(w[i], h[r], acc[i][r]);
    }
    #pragma unroll
    for (int i = 0; i < 8; ++i) {
        int g = gbase + gg + 32 * i;
        float bias = bih1[g];
        #pragma unroll
        for (int r = 0; r < 4; ++r)
            xg[(size_t)(m0 + mg * 4 + r) * G_ + g] = acc[i][r] + bias;
    }
}

__device__ __forceinline__ void reg_body(const f16* __restrict__ h2,
        const uint32_t* __restrict__ w1T, const float* __restrict__ b1,
        const float* __restrict__ w2, const float* __restrict__ b2,
        float* __restrict__ out, int t0, int C, int lgC, int blk, char* smem) {
    u32x4 (*hs)[32] = (u32x4(*)[32])smem;            // 32 KB
    float (*red)[4] = (float(*)[4])(smem + 32768);   // [16][4]
    int tid = threadIdx.x;
    int m0 = blk * 64;
    const u32x4* hsrc = (const u32x4*)h2 + (size_t)m0 * 32;
    #pragma unroll
    for (int it = 0; it < 4; ++it) {
        int o = tid + it * 512;
        hs[o >> 5][o & 31] = hsrc[o];
    }
    __syncthreads();
    int gg = tid & 31, mg = tid >> 5;
    const u32x4* wt = (const u32x4*)w1T;
    float acc[8][4];
    #pragma unroll
    for (int i = 0; i < 8; ++i)
        #pragma unroll
        for (int r = 0; r < 4; ++r) acc[i][r] = 0.0f;
    for (int k8 = 0; k8 < 32; ++k8) {
        u32x4 w[8], h[4];
        #pragma unroll
        for (int i = 0; i < 8; ++i) w[i] = wt[(size_t)k8 * 256 + gg + 32 * i];
        #pragma unroll
        for (int r = 0; r < 4; ++r) h[r] = hs[mg * 4 + r][k8];
        #pragma unroll
        for (int i = 0; i < 8; ++i)
            #pragma unroll
            for (int r = 0; r < 4; ++r)
                acc[i][r] = dot_u4(w[i], h[r], acc[i][r]);
    }
    float pv[4] = {0, 0, 0, 0};
    #pragma unroll
    for (int i = 0; i < 8; ++i) {
        int g = gg + 32 * i;
        float bias = b1[g], w2g = w2[g];
        #pragma unroll
        for (int r = 0; r < 4; ++r)
            pv[r] += w2g * fmaxf(acc[i][r] + bias, 0.0f);
    }
    #pragma unroll
    for (int r = 0; r < 4; ++r) {
        pv[r] += __shfl_xor(pv[r], 1, 64);
        pv[r] += __shfl_xor(pv[r], 2, 64);
        pv[r] += __shfl_xor(pv[r], 4, 64);
        pv[r] += __shfl_xor(pv[r], 8, 64);
        pv[r] += __shfl_xor(pv[r], 16, 64);
    }
    if (gg == 0) {
        #pragma unroll
        for (int r = 0; r < 4; ++r) red[mg][r] = pv[r];
    }
    __syncthreads();
    if (tid < 64) {
        int m = m0 + tid;
        float v = fmaxf(red[tid >> 2][tid & 3] + b2[0], 0.0f);
        int b = m >> lgC, tl = m & (C - 1);
        out[(size_t)b * T_ + t0 + tl] = v;
    }
}

// ---------- GRU recurrence ----------
// Split: z u0..11 VGPR (fp16) | n u0..15 + z u12..14 LDS (19 slabs, fp16)
//        | r u0..15 streamed fp8-e5m2 + z u15 streamed fp16.
// e5m2 -> f16 decode is exact: f16 = byte << 8 (one __byte_perm per pair).
__device__ __forceinline__ void rec_body(const uint32_t* __restrict__ whh,
        const float* __restrict__ bhh, const float* __restrict__ xg,
        f16* __restrict__ hout, float* __restrict__ state,
        int b, int C, char* smem) {
    int tid = threadIdx.x;
    int j = tid >> 1, hf = tid & 1;
    const u32x4* wb = (const u32x4*)whh;              // fp16 planes
    const u32x2* w8 = (const u32x2*)(whh + 65536);    // fp8 r planes
    u32x4* wlds = (u32x4*)smem;                       // 19 slabs x [512]
    u32x4 (*hq)[2][17] = (u32x4(*)[2][17])(smem + 155648);

    // stage slabs thread-major: 0..15 = n (P=16..31), 16..18 = z u12..14 (P=12..14)
    #pragma unroll
    for (int s = 0; s < 16; ++s)
        wlds[s * 512 + tid] = wb[(16 + s) * 512 + tid];
    #pragma unroll
    for (int s = 0; s < 3; ++s)
        wlds[(16 + s) * 512 + tid] = wb[(12 + s) * 512 + tid];

    // resident z u0..11
    u32x4 Z0  = wb[ 0 * 512 + tid], Z1  = wb[ 1 * 512 + tid];
    u32x4 Z2  = wb[ 2 * 512 + tid], Z3  = wb[ 3 * 512 + tid];
    u32x4 Z4  = wb[ 4 * 512 + tid], Z5  = wb[ 5 * 512 + tid];
    u32x4 Z6  = wb[ 6 * 512 + tid], Z7  = wb[ 7 * 512 + tid];
    u32x4 Z8  = wb[ 8 * 512 + tid], Z9  = wb[ 9 * 512 + tid];
    u32x4 Z10 = wb[10 * 512 + tid], Z11 = wb[11 * 512 + tid];

    float h_old = 0.0f, bhr = 0.0f, bhz = 0.0f, bhn = 0.0f;
    if (hf == 0) {
        h_old = state[b * 256 + j];
        bhr = bhh[j]; bhz = bhh[256 + j]; bhn = bhh[512 + j];
        ((f16*)&hq[0][j >> 7][0])[j & 127] = (f16)h_old;
    }
    __syncthreads();

    const float* xgt = xg + (size_t)b * C * G_;
    f16* hob = hout + (size_t)b * C * H_;
    const u32x4* nl = wlds + tid;

    for (int tl = 0; tl < C; ++tl) {
        int p = tl & 1;
        // issue all streamed loads up-front (16 fp8 pairs + 1 fp16 quad + xg)
        u32x2 F0  = w8[ 0 * 512 + tid], F1  = w8[ 1 * 512 + tid];
        u32x2 F2  = w8[ 2 * 512 + tid], F3  = w8[ 3 * 512 + tid];
        u32x2 F4  = w8[ 4 * 512 + tid], F5  = w8[ 5 * 512 + tid];
        u32x2 F6  = w8[ 6 * 512 + tid], F7  = w8[ 7 * 512 + tid];
        u32x2 F8  = w8[ 8 * 512 + tid], F9  = w8[ 9 * 512 + tid];
        u32x2 F10 = w8[10 * 512 + tid], F11 = w8[11 * 512 + tid];
        u32x2 F12 = w8[12 * 512 + tid], F13 = w8[13 * 512 + tid];
        u32x2 F14 = w8[14 * 512 + tid], F15 = w8[15 * 512 + tid];
        u32x4 SZ = wb[15 * 512 + tid];
        float xr = 0, xz = 0, xn = 0;
        if (hf == 0) { xr = xgt[j]; xz = xgt[256 + j]; xn = xgt[512 + j]; }

        const u32x4* hp = &hq[p][hf][0];
        float aR = 0.0f, aZ = 0.0f, aN = 0.0f;

#define PU(u, ZS) { u32x4 hv = hp[u]; \
        aN = dot_u4(nl[(u) * 512], hv, aN); \
        aZ = dot_u4(ZS, hv, aZ); \
        u32x4 wr; \
        wr.x = __byte_perm(F##u.x, 0u, 0x1404); \
        wr.y = __byte_perm(F##u.x, 0u, 0x3424); \
        wr.z = __byte_perm(F##u.y, 0u, 0x1404); \
        wr.w = __byte_perm(F##u.y, 0u, 0x3424); \
        aR = dot_u4(wr, hv, aR); }

        PU(0,  Z0)  PU(1,  Z1)  PU(2,  Z2)  PU(3,  Z3)
        PU(4,  Z4)  PU(5,  Z5)  PU(6,  Z6)  PU(7,  Z7)
        PU(8,  Z8)  PU(9,  Z9)  PU(10, Z10) PU(11, Z11)
        PU(12, nl[16 * 512]) PU(13, nl[17 * 512]) PU(14, nl[18 * 512])
        PU(15, SZ)
#undef PU

        // combine the two K-halves (adjacent lanes 2j / 2j+1)
        aR += __shfl_xor(aR, 1, 64);
        aZ += __shfl_xor(aZ, 1, 64);
        aN += __shfl_xor(aN, 1, 64);

        if (hf == 0) {
            float r = sigmoid_f(xr + aR + bhr);
            float z = sigmoid_f(xz + aZ + bhz);
            float n = tanh_f(xn + r * (aN + bhn));
            h_old = z * (h_old - n) + n;   // (1-z)*n + z*h
            f16 hh = (f16)h_old;
            hob[(size_t)tl * H_ + j] = hh;
            ((f16*)&hq[p ^ 1][j >> 7][0])[j & 127] = hh;
        }
        __syncthreads();
        xgt += G_;
    }
    if (hf == 0) state[b * 256 + j] = h_old;
}

// =======================================================================
// fused dispatch, depth-3 pipeline (roles as in R11)
// =======================================================================
__global__ __launch_bounds__(512)
__attribute__((amdgpu_waves_per_eu(2, 2)))
void fused_step(int i, int nC, int C, int lgC,
        const float* __restrict__ x,
        const float* __restrict__ wih0, const float* __restrict__ bih0,
        const uint32_t* __restrict__ whh0, const float* __restrict__ bhh0,
        const uint32_t* __restrict__ whh1, const float* __restrict__ bhh1,
        const uint32_t* __restrict__ wih1T, const float* __restrict__ bih1,
        const uint32_t* __restrict__ w1T, const float* __restrict__ b1,
        const float* __restrict__ w2, const float* __restrict__ b2,
        float* __restrict__ xg0a, float* __restrict__ xg0b,
        float* __restrict__ xg1a, float* __restrict__ xg1b,
        f16* __restrict__ h1a, f16* __restrict__ h1b,
        f16* __restrict__ h2a, f16* __restrict__ h2b,
        float* __restrict__ st0, float* __restrict__ st1,
        float* __restrict__ out) {
    extern __shared__ __align__(16) char smem[];
    int blk = blockIdx.x;
    if (blk < 64) {
        if (i >= nC) return;
        rec_body(whh0, bhh0, (i & 1) ? xg0b : xg0a,
                 (i & 1) ? h1b : h1a, st0, blk, C, smem);
    } else if (blk < 128) {
        int c = i - 2;
        if (c < 0 || c >= nC) return;
        rec_body(whh1, bhh1, (c & 1) ? xg1b : xg1a,
                 (c & 1) ? h2b : h2a, st1, blk - 64, C, smem);
    } else if (blk < 128 + C) {
        int c = i + 1;
        if (c >= nC) return;
        xg0_body(x, wih0, bih0, (c & 1) ? xg0b : xg0a, c * C, C, blk - 128, smem);
    } else if (blk < 128 + 4 * C) {
        int c = i - 1;
        if (c < 0 || c >= nC) return;
        xg1_body((c & 1) ? h1b : h1a, wih1T, bih1,
                 (c & 1) ? xg1b : xg1a, C, lgC, blk - 128 - C, smem);
    } else {
        int c = i - 3;
        if (c < 0 || c >= nC) return;
        reg_body((c & 1) ? h2b : h2a, w1T, b1, w2, b2, out, c * C, C, lgC,
                 blk - 128 - 4 * C, smem);
    }
}

// ---------- standalone xg0 (chunk 0 prelaunch) ----------
__global__ __launch_bounds__(512) void xg0_stand(const float* __restrict__ x,
        const float* __restrict__ wih0, const float* __restrict__ bih0,
        float* __restrict__ xg, int t0, int C) {
    __shared__ __align__(16) char smem[4096];
    xg0_body(x, wih0, bih0, xg, t0, C, blockIdx.x, smem);
}

// ---------- host ----------
extern "C" void kernel_launch(void* const* d_in, const int* in_sizes, int n_in,
                              void* d_out, int out_size, void* d_ws, size_t ws_size,
                              hipStream_t stream) {
    const float* x    = (const float*)d_in[0];
    const float* Wih0 = (const float*)d_in[1];
    const float* Whh0 = (const float*)d_in[2];
    const float* bih0 = (const float*)d_in[3];
    const float* bhh0 = (const float*)d_in[4];
    const float* Wih1 = (const float*)d_in[5];
    const float* Whh1 = (const float*)d_in[6];
    const float* bih1 = (const float*)d_in[7];
    const float* bhh1 = (const float*)d_in[8];
    const float* W1   = (const float*)d_in[9];
    const float* b1   = (const float*)d_in[10];
    const float* W2   = (const float*)d_in[11];
    const float* b2   = (const float*)d_in[12];
    float* out = (float*)d_out;

    hipFuncSetAttribute(reinterpret_cast<const void*>(fused_step),
                        hipFuncAttributeMaxDynamicSharedMemorySize, REC_SMEM);

    char* ws = (char*)d_ws;
    uint32_t* wcvt = (uint32_t*)ws;             // 294912 dwords
    const uint32_t* whh0c = wcvt;
    const uint32_t* whh1c = wcvt + 81920;
    const uint32_t* wih1T = wcvt + 163840;
    const uint32_t* w1T   = wcvt + 262144;
    float* state0 = (float*)(ws + 1179648);
    float* state1 = (float*)(ws + 1179648 + 65536);
    size_t fixed = 1179648 + 2 * 65536;

    // per-chunk: xg0 x2 + xg1 x2 (196608C each) + h1 x2 + h2 x2 (32768C each)
    int C = 128;
    while (C > 32 && fixed + (size_t)C * 917504 > ws_size) C >>= 1;
    int lgC = 0; while ((1 << lgC) < C) lgC++;
    int nC = T_ / C;

    char* p = ws + fixed;
    float* xg0_buf[2]; float* xg1_buf[2];
    f16* h1_buf[2]; f16* h2_buf[2];
    xg0_buf[0] = (float*)p;  p += (size_t)C * 196608;
    xg0_buf[1] = (float*)p;  p += (size_t)C * 196608;
    xg1_buf[0] = (float*)p;  p += (size_t)C * 196608;
    xg1_buf[1] = (float*)p;  p += (size_t)C * 196608;
    h1_buf[0] = (f16*)p;     p += (size_t)C * 32768;
    h1_buf[1] = (f16*)p;     p += (size_t)C * 32768;
    h2_buf[0] = (f16*)p;     p += (size_t)C * 32768;
    h2_buf[1] = (f16*)p;

    cvt_weights<<<1152, 256, 0, stream>>>(Whh0, Whh1, Wih1, W1, wcvt);
    hipMemsetAsync(state0, 0, 2 * 65536, stream);
    xg0_stand<<<C, 512, 0, stream>>>(x, Wih0, bih0, xg0_buf[0], 0, C);

    for (int i = 0; i <= nC + 2; ++i) {
        fused_step<<<128 + 5 * C, 512, REC_SMEM, stream>>>(i, nC, C, lgC,
            x, Wih0, bih0, whh0c, bhh0, whh1c, bhh1, wih1T, bih1, w1T, b1, W2, b2,
            xg0_buf[0], xg0_buf[1], xg1_buf[0], xg1_buf[1],
            h1_buf[0], h1_buf[1], h2_buf[0], h2_buf[1],
            state0, state1, out);
    }
}